// Round 5
// baseline (1032.480 us; speedup 1.0000x reference)
//
#include <hip/hip_runtime.h>
#include <math.h>

#define BATCH 32
#define TSEQ  4096
#define HD    128
#define NST   128
#define BT    (BATCH*TSEQ)     // 131072
#define LC    64               // scan chunk length
#define NCHK  (TSEQ/LC)        // 64 chunks

typedef unsigned short bf16;
typedef __attribute__((ext_vector_type(8))) short bf16x8;   // 8 bf16 = 4 VGPRs (MFMA A/B frag)
typedef __attribute__((ext_vector_type(4))) float f32x4;    // MFMA C/D frag

union bf8u { bf16x8 v; ushort4 u4[2]; };

__device__ inline float bf2f(bf16 s) {
    union { unsigned int u; float f; } v; v.u = ((unsigned int)s) << 16; return v.f;
}
__device__ inline bf16 f2bf(float f) {
    union { float f; unsigned int u; } v; v.f = f;
    unsigned int u = v.u;
    unsigned int r = (u + 0x7fffu + ((u >> 16) & 1u)) >> 16;
    return (bf16)r;
}
__device__ inline float2 cmul2(float2 a, float2 b) {
    return make_float2(a.x*b.x - a.y*b.y, a.x*b.y + a.y*b.x);
}
__device__ inline float gelu_f(float x) {
    return 0.5f * x * (1.f + erff(x * 0.70710678118654752f));
}

// ---------------- S5 parameter prep (bf16, transposed [N][K] for MFMA B) ----------------
__global__ void prep_s5(const float* __restrict__ Lam_re, const float* __restrict__ Lam_im,
                        const float* __restrict__ B_re,  const float* __restrict__ B_im,
                        const float* __restrict__ C_re,  const float* __restrict__ C_im,
                        const float* __restrict__ log_step,
                        bf16* __restrict__ Wbu_t,   // [2][256][128]  row 2n=Re, 2n+1=Im
                        bf16* __restrict__ Wc_t,    // [2][128][256]  col 2n=2Cre, 2n+1=-2Cim
                        float4* __restrict__ coefs)
{
    int i = blockIdx.x;          // layer
    int n = threadIdx.x;         // state
    int in = i*NST + n;
    float lr = Lam_re[in], li = Lam_im[in];
    float dt = expf(log_step[in]);
    float ldr = lr*dt, ldi = li*dt;
    float ea = expf(ldr);
    float ar = ea*cosf(ldi), ai = ea*sinf(ldi);
    float xx = ar - 1.f, yy = ai;
    float den = lr*lr + li*li;
    float sr = (xx*lr + yy*li)/den;
    float si = (yy*lr - xx*li)/den;
    float2 p = make_float2(ar, ai);
    #pragma unroll
    for (int q = 0; q < 6; ++q) p = cmul2(p, p);   // a^64
    coefs[in] = make_float4(ar, ai, p.x, p.y);

    const float* br = B_re + (size_t)in*HD;
    const float* bi = B_im + (size_t)in*HD;
    bf16* wb = Wbu_t + (size_t)i*256*128;
    for (int h = 0; h < HD; ++h) {
        float brv = br[h], biv = bi[h];
        wb[(2*n)*128 + h]   = f2bf(sr*brv - si*biv);
        wb[(2*n+1)*128 + h] = f2bf(sr*biv + si*brv);
    }
    const float* cr = C_re + (size_t)i*HD*NST;
    const float* ci = C_im + (size_t)i*HD*NST;
    bf16* wc = Wc_t + (size_t)i*128*256;
    for (int h = 0; h < HD; ++h) {
        wc[h*256 + 2*n]   = f2bf( 2.f * cr[h*NST + n]);
        wc[h*256 + 2*n+1] = f2bf(-2.f * ci[h*NST + n]);
    }
}

// MLP weights -> bf16 transposed [N][K]
__global__ void prep_w12(const float* __restrict__ W1, const float* __restrict__ W2,
                         bf16* __restrict__ W1t, bf16* __restrict__ W2t)
{
    int idx = blockIdx.x*256 + threadIdx.x;
    if (idx < 65536) {                       // W1t[i][f][h] = W1[i][h][f]
        int i = idx >> 15, r = idx & 32767;
        int f = r >> 7, h = r & 127;
        W1t[idx] = f2bf(W1[(size_t)i*32768 + h*256 + f]);
    } else if (idx < 131072) {               // W2t[i][h][f] = W2[i][f][h]
        int t = idx - 65536;
        int i = t >> 15, r = t & 32767;
        int h = r >> 8, f = r & 255;
        W2t[t] = f2bf(W2[(size_t)i*32768 + f*128 + h]);
    }
}

// conv weights [c][ic][tap] -> bf16 [c][tap*128+ic]  (im2col B-matrix, K=640)
__global__ void prep_wB(const float* __restrict__ w1, const float* __restrict__ w2,
                        bf16* __restrict__ wB1, bf16* __restrict__ wB2)
{
    int idx = blockIdx.x*256 + threadIdx.x;
    if (idx >= 163840) return;
    const float* w = (idx < 81920) ? w1 : w2;
    bf16* wb       = (idx < 81920) ? wB1 : wB2;
    int r   = idx % 81920;
    int c   = r / 640;
    int tap = (r % 640) / 128;
    int ic  = r % 128;
    wb[r] = f2bf(w[(c*128 + ic)*5 + tap]);
}

// ---------------- LayerNorm (H=128): one wave per row, bf16 out ----------------
__global__ __launch_bounds__(256) void ln_kernel(const float* __restrict__ X,
                                                 bf16* __restrict__ out,
                                                 const float* __restrict__ g,
                                                 const float* __restrict__ b)
{
    int lane = threadIdx.x & 63;
    size_t row = (size_t)blockIdx.x*4 + (threadIdx.x >> 6);
    const float* xr = X + row*HD;
    float2 v = *(const float2*)&xr[lane*2];
    float s = v.x + v.y;
    float s2 = v.x*v.x + v.y*v.y;
    #pragma unroll
    for (int off = 32; off >= 1; off >>= 1) {
        s  += __shfl_xor(s,  off);
        s2 += __shfl_xor(s2, off);
    }
    float mu  = s * (1.f/128.f);
    float var = s2 * (1.f/128.f) - mu*mu;
    float rs  = rsqrtf(var + 1e-5f);
    float2 gv = *(const float2*)&g[lane*2];
    float2 bv = *(const float2*)&b[lane*2];
    float ox = (v.x-mu)*rs*gv.x + bv.x;
    float oy = (v.y-mu)*rs*gv.y + bv.y;
    *(ushort2*)&out[row*HD + lane*2] = make_ushort2(f2bf(ox), f2bf(oy));
}

// ---------------- persistent-wave MFMA GEMM: B in LDS, A global->reg, no loop barriers ----
// A: [BT,K] (bf16 or fp32). Bt: [NCOL][K] bf16. out fp32 [BT,NCOL].
// EPI: 0 none; 1 gelu(acc+bias); 2 acc+bias+resid; 3 resid+acc+u*dskip
// Grid: 1024 blocks x 256 thr = 4096 waves; strips = BT/16 = 8192 -> 2 strips/wave.
template<int K, int NCOL, int EPI, typename TA>
__global__ __launch_bounds__(256) void gemm_wave(
    const TA*  __restrict__ A,
    const bf16* __restrict__ Bt,
    float* out,                      // may alias resid (same-element read-then-write only)
    const float* __restrict__ bias,
    const float* resid,
    const bf16* __restrict__ u,
    const float* __restrict__ dskip)
{
    constexpr int KS = K / 32;       // k-steps
    constexpr int NT = NCOL / 16;    // n-tiles
    constexpr int KP = K + 8;        // padded row (2-way LDS aliasing only)
    __shared__ bf16 Bs[NCOL * KP];

    int tid  = threadIdx.x;
    // stage all of B once (64 KB)
    for (int f = tid; f < NCOL*K/8; f += 256) {
        int n  = f / (K/8);
        int kk = (f % (K/8)) * 8;
        *(bf16x8*)&Bs[n*KP + kk] = *(const bf16x8*)(Bt + (size_t)n*K + kk);
    }
    __syncthreads();

    int lane = tid & 63;
    int quad = lane >> 4, cl = lane & 15;
    int wg = blockIdx.x*4 + (tid >> 6);          // 0..4095

    auto loadA = [&](int s, bf16x8* dst) {
        const size_t base = (size_t)(s*16 + cl)*K + quad*8;
        #pragma unroll
        for (int ks = 0; ks < KS; ++ks) {
            if constexpr (sizeof(TA) == 2) {
                dst[ks] = *(const bf16x8*)(A + base + ks*32);
            } else {
                float4 f0 = *(const float4*)(A + base + ks*32);
                float4 f1 = *(const float4*)(A + base + ks*32 + 4);
                bf8u t;
                t.u4[0] = make_ushort4(f2bf(f0.x), f2bf(f0.y), f2bf(f0.z), f2bf(f0.w));
                t.u4[1] = make_ushort4(f2bf(f1.x), f2bf(f1.y), f2bf(f1.z), f2bf(f1.w));
                dst[ks] = t.v;
            }
        }
    };

    auto compute = [&](int s, bf16x8* af) {
        f32x4 acc[NT] = {};
        #pragma unroll
        for (int nt = 0; nt < NT; ++nt) {
            const bf16* brow = &Bs[(nt*16 + cl)*KP + quad*8];
            #pragma unroll
            for (int ks = 0; ks < KS; ++ks) {
                bf16x8 bfr = *(const bf16x8*)(brow + ks*32);
                acc[nt] = __builtin_amdgcn_mfma_f32_16x16x32_bf16(af[ks], bfr, acc[nt], 0, 0, 0);
            }
        }
        // epilogue: C/D layout col=lane&15, row=quad*4+reg
        #pragma unroll
        for (int nt = 0; nt < NT; ++nt) {
            int col = nt*16 + cl;
            float bv = (EPI == 1 || EPI == 2) ? bias[col] : 0.f;
            float dv = (EPI == 3) ? dskip[col] : 0.f;
            #pragma unroll
            for (int r = 0; r < 4; ++r) {
                size_t row  = (size_t)s*16 + quad*4 + r;
                size_t oidx = row*NCOL + col;
                float v = acc[nt][r];
                if (EPI == 1)      v = gelu_f(v + bv);
                else if (EPI == 2) v = v + bv + resid[oidx];
                else if (EPI == 3) v = resid[oidx] + v + bf2f(u[oidx])*dv;
                out[oidx] = v;
            }
        }
    };

    bf16x8 af0[KS], af1[KS];
    loadA(wg, af0);
    loadA(wg + 4096, af1);       // prefetch strip 2 before strip-1 compute
    compute(wg, af0);
    compute(wg + 4096, af1);
}

// ---------------- conv1d stride2 k=5 pad2 as implicit-im2col MFMA GEMM ----------------
__global__ __launch_bounds__(256) void conv_mfma(
    const float* __restrict__ X,
    const bf16* __restrict__ wB,    // [128][640]
    const float* __restrict__ bias,
    float* __restrict__ out,        // [B*Lout][128]
    int Tin, int Lout)
{
    __shared__ bf16 As[128][72];
    __shared__ bf16 Bs[128][72];
    int tid  = threadIdx.x;
    int lane = tid & 63;
    int wave = tid >> 6;
    int wm = wave >> 1, wn = wave & 1;
    int quad = lane >> 4, cl = lane & 15;
    int row0 = blockIdx.x * 128;               // global output row (Lout % 128 == 0)
    int b  = row0 / Lout;
    int l0 = row0 % Lout;
    const float* Xb = X + (size_t)b*Tin*128;

    f32x4 acc[4][4] = {};

    for (int k0 = 0; k0 < 640; k0 += 64) {
        int tap = k0 / 128;                    // 64-chunk never crosses a tap
        int icb = k0 % 128;
        #pragma unroll
        for (int it = 0; it < 8; ++it) {
            int idx = it*256 + tid;
            int r = idx >> 4, kof = (idx & 15) * 4;
            int t = 2*(l0 + r) - 2 + tap;
            ushort4 h = make_ushort4(0,0,0,0);
            if (t >= 0 && t < Tin) {
                float4 f = *(const float4*)(Xb + (size_t)t*128 + icb + kof);
                h.x = f2bf(f.x); h.y = f2bf(f.y); h.z = f2bf(f.z); h.w = f2bf(f.w);
            }
            *(ushort4*)&As[r][kof] = h;
        }
        #pragma unroll
        for (int it = 0; it < 4; ++it) {
            int idx = it*256 + tid;
            int n = idx >> 3, kof = (idx & 7) * 8;
            *(bf16x8*)&Bs[n][kof] = *(const bf16x8*)(wB + (size_t)n*640 + k0 + kof);
        }
        __syncthreads();
        #pragma unroll
        for (int kk = 0; kk < 64; kk += 32) {
            bf16x8 af[4], bfr[4];
            #pragma unroll
            for (int i = 0; i < 4; ++i)
                af[i] = *(const bf16x8*)&As[wm*64 + i*16 + cl][kk + quad*8];
            #pragma unroll
            for (int j = 0; j < 4; ++j)
                bfr[j] = *(const bf16x8*)&Bs[wn*64 + j*16 + cl][kk + quad*8];
            #pragma unroll
            for (int i = 0; i < 4; ++i)
                #pragma unroll
                for (int j = 0; j < 4; ++j)
                    acc[i][j] = __builtin_amdgcn_mfma_f32_16x16x32_bf16(
                                    af[i], bfr[j], acc[i][j], 0, 0, 0);
        }
        __syncthreads();
    }

    #pragma unroll
    for (int j = 0; j < 4; ++j) {
        int gcol = wn*64 + j*16 + cl;
        float bv = bias[gcol];
        #pragma unroll
        for (int i = 0; i < 4; ++i) {
            #pragma unroll
            for (int r = 0; r < 4; ++r) {
                int grow = row0 + wm*64 + i*16 + quad*4 + r;
                float v = acc[i][j][r] + bv;
                out[(size_t)grow*128 + gcol] = v > 0.f ? v : 0.f;
            }
        }
    }
}

// ---------------- chunked scan: x_t = a*x_{t-1} + Bu_t (fp32) ----------------
__global__ __launch_bounds__(256) void scan_local(float2* __restrict__ xs,
                                                  const float4* __restrict__ coefs,
                                                  float2* __restrict__ carry)
{
    int flat = blockIdx.x*256 + threadIdx.x;  // 2^18
    int n = flat & 127;
    int b = (flat >> 7) & 31;
    int c = flat >> 12;
    float4 cf = coefs[n];
    float2 a = make_float2(cf.x, cf.y);
    float2* base = xs + ((size_t)(b*TSEQ + c*LC))*NST + n;
    float2 x = make_float2(0.f, 0.f);
    for (int j = 0; j < LC; ++j) {
        float2 v = base[(size_t)j*NST];
        x = make_float2(a.x*x.x - a.y*x.y + v.x, a.x*x.y + a.y*x.x + v.y);
        base[(size_t)j*NST] = x;
    }
    carry[c*(BATCH*NST) + b*NST + n] = x;
}

__global__ void scan_carry(float2* __restrict__ carry, const float4* __restrict__ coefs)
{
    int flat = blockIdx.x*256 + threadIdx.x;  // 4096 = B*N
    int n = flat & 127;
    float4 cf = coefs[n];
    float2 aL = make_float2(cf.z, cf.w);
    float2 x = make_float2(0.f, 0.f);
    for (int c = 0; c < NCHK; ++c) {
        float2* p = carry + c*(BATCH*NST) + flat;
        float2 v = *p;
        *p = x;                                // exclusive prefix
        x = make_float2(aL.x*x.x - aL.y*x.y + v.x, aL.x*x.y + aL.y*x.x + v.y);
    }
}

__global__ __launch_bounds__(256) void scan_fix(float2* __restrict__ xs,
                                                const float4* __restrict__ coefs,
                                                const float2* __restrict__ carry)
{
    int flat = blockIdx.x*256 + threadIdx.x;
    int n = flat & 127;
    int b = (flat >> 7) & 31;
    int c = flat >> 12;
    if (c == 0) return;
    float2 cin = carry[c*(BATCH*NST) + b*NST + n];
    float4 cf = coefs[n];
    float2 a = make_float2(cf.x, cf.y);
    float2* base = xs + ((size_t)(b*TSEQ + c*LC))*NST + n;
    float2 p = a;
    for (int j = 0; j < LC; ++j) {
        float2 add = cmul2(p, cin);
        float2 v = base[(size_t)j*NST];
        base[(size_t)j*NST] = make_float2(v.x + add.x, v.y + add.y);
        p = cmul2(p, a);
    }
}

// ---------------- adaptive avg pool: [32][1024][128] -> [32][128][64] ----------------
__global__ void pool_kernel(const float* __restrict__ Xc, float* __restrict__ out)
{
    int idx = blockIdx.x*256 + threadIdx.x;   // 262144
    int c = idx & 127;
    int d = (idx >> 7) & 63;
    int b = idx >> 13;
    float s = 0.f;
    #pragma unroll
    for (int j = 0; j < 16; ++j)
        s += Xc[((size_t)b*1024 + d*16 + j)*128 + c];
    out[((size_t)b*128 + c)*64 + d] = s * (1.f/16.f);
}

extern "C" void kernel_launch(void* const* d_in, const int* in_sizes, int n_in,
                              void* d_out, int out_size, void* d_ws, size_t ws_size,
                              hipStream_t stream)
{
    (void)in_sizes; (void)n_in; (void)out_size; (void)ws_size;
    const float* x_in    = (const float*)d_in[0];
    const float* ln1_g   = (const float*)d_in[1];
    const float* ln1_b   = (const float*)d_in[2];
    const float* ln2_g   = (const float*)d_in[3];
    const float* ln2_b   = (const float*)d_in[4];
    const float* Lam_re  = (const float*)d_in[5];
    const float* Lam_im  = (const float*)d_in[6];
    const float* B_re    = (const float*)d_in[7];
    const float* B_im    = (const float*)d_in[8];
    const float* C_re    = (const float*)d_in[9];
    const float* C_im    = (const float*)d_in[10];
    const float* D_skip  = (const float*)d_in[11];
    const float* log_step= (const float*)d_in[12];
    const float* W1      = (const float*)d_in[13];
    const float* b1      = (const float*)d_in[14];
    const float* W2      = (const float*)d_in[15];
    const float* b2      = (const float*)d_in[16];
    const float* conv1_w = (const float*)d_in[17];
    const float* conv1_b = (const float*)d_in[18];
    const float* conv2_w = (const float*)d_in[19];
    const float* conv2_b = (const float*)d_in[20];
    float* out = (float*)d_out;

    // Workspace: X fp32 64MB @0 | C fp32 [BT,256] 128MB @64MB | Abf bf16 32MB @192MB
    //            | params+carry ~2.95MB @224MB
    char* ws = (char*)d_ws;
    float* X   = (float*)(ws);
    float* C   = (float*)(ws + (size_t)67108864);
    bf16*  Abf = (bf16*) (ws + (size_t)201326592);
    char*  wreg = ws + (size_t)234881024;
    bf16*   Wbu_t = (bf16*)(wreg);                  // 131072 B
    bf16*   Wc_t  = (bf16*)(wreg + 131072);         // 131072 B
    bf16*   W1t   = (bf16*)(wreg + 262144);         // 131072 B
    bf16*   W2t   = (bf16*)(wreg + 393216);         // 131072 B
    float4* coefs = (float4*)(wreg + 524288);       // 4096 B
    bf16*   wB1   = (bf16*)(wreg + 528384);         // 163840 B
    bf16*   wB2   = (bf16*)(wreg + 692224);         // 163840 B
    float2* carry = (float2*)(wreg + 856064);       // 2 MB

    prep_s5<<<2, 128, 0, stream>>>(Lam_re, Lam_im, B_re, B_im, C_re, C_im, log_step,
                                   Wbu_t, Wc_t, coefs);
    prep_w12<<<512, 256, 0, stream>>>(W1, W2, W1t, W2t);
    prep_wB<<<640, 256, 0, stream>>>(conv1_w, conv2_w, wB1, wB2);

    for (int i = 0; i < 2; ++i) {
        const float* src = (i == 0) ? x_in : X;     // layer input / residual
        // ---- S5 sub-block ----
        ln_kernel<<<BT/4, 256, 0, stream>>>(src, Abf, ln1_g + i*HD, ln1_b + i*HD);
        gemm_wave<128,256,0,bf16><<<1024, 256, 0, stream>>>(
            Abf, Wbu_t + (size_t)i*256*128, C, nullptr, nullptr, nullptr, nullptr);
        scan_local<<<1024, 256, 0, stream>>>((float2*)C, coefs + i*NST, carry);
        scan_carry<<<16, 256, 0, stream>>>(carry, coefs + i*NST);
        scan_fix<<<1024, 256, 0, stream>>>((float2*)C, coefs + i*NST, carry);
        gemm_wave<256,128,3,float><<<1024, 256, 0, stream>>>(
            C, Wc_t + (size_t)i*128*256, X, nullptr, src, Abf, D_skip + i*HD);
        // ---- MLP sub-block ----
        ln_kernel<<<BT/4, 256, 0, stream>>>(X, Abf, ln2_g + i*HD, ln2_b + i*HD);
        gemm_wave<128,256,1,bf16><<<1024, 256, 0, stream>>>(
            Abf, W1t + (size_t)i*256*128, C, b1 + i*2*HD, nullptr, nullptr, nullptr);
        gemm_wave<256,128,2,float><<<1024, 256, 0, stream>>>(
            C, W2t + (size_t)i*128*256, X, b2 + i*HD, X, nullptr, nullptr);
    }

    // ---- head: conv1 (X->C) -> conv2 (C->X) -> pool (X->out) ----
    conv_mfma<<<512, 256, 0, stream>>>(X, wB1, conv1_b, C, 4096, 2048);
    conv_mfma<<<256, 256, 0, stream>>>(C, wB2, conv2_b, X, 2048, 1024);
    pool_kernel<<<1024, 256, 0, stream>>>(X, out);
}

// Round 6
// 717.307 us; speedup vs baseline: 1.4394x; 1.4394x over previous
//
#include <hip/hip_runtime.h>
#include <math.h>

#define BATCH 32
#define TSEQ  4096
#define HD    128
#define NST   128
#define BT    (BATCH*TSEQ)     // 131072
#define LC    64               // scan chunk length
#define NCHK  (TSEQ/LC)        // 64 chunks

typedef unsigned short bf16;
typedef __attribute__((ext_vector_type(8))) short bf16x8;   // 8 bf16 = 4 VGPRs (MFMA A/B frag)
typedef __attribute__((ext_vector_type(4))) float f32x4;    // MFMA C/D frag

__device__ inline float bf2f(bf16 s) {
    union { unsigned int u; float f; } v; v.u = ((unsigned int)s) << 16; return v.f;
}
__device__ inline bf16 f2bf(float f) {
    union { float f; unsigned int u; } v; v.f = f;
    unsigned int u = v.u;
    unsigned int r = (u + 0x7fffu + ((u >> 16) & 1u)) >> 16;
    return (bf16)r;
}
__device__ inline bf16x8 pack8(const float* f) {
    union { bf16x8 v; ushort u[8]; } t;
    #pragma unroll
    for (int j = 0; j < 8; ++j) t.u[j] = f2bf(f[j]);
    return t.v;
}
__device__ inline float2 cmul2(float2 a, float2 b) {
    return make_float2(a.x*b.x - a.y*b.y, a.x*b.y + a.y*b.x);
}
__device__ inline float gelu_f(float x) {
    return 0.5f * x * (1.f + erff(x * 0.70710678118654752f));
}
__device__ inline float2 upk(unsigned int w) {     // bf16 pair -> fp32 pair
    union { unsigned int u; float f; } a, b;
    a.u = w << 16; b.u = w & 0xffff0000u;
    return make_float2(a.f, b.f);
}
__device__ inline unsigned int pk(float2 x) {
    return ((unsigned int)f2bf(x.x)) | (((unsigned int)f2bf(x.y)) << 16);
}

// ---------------- S5 param prep: g-folded W'bu, S/bias corrections, Wc, gd/bd, coefs ----
__global__ void prep_s5(const float* __restrict__ Lam_re, const float* __restrict__ Lam_im,
                        const float* __restrict__ B_re,  const float* __restrict__ B_im,
                        const float* __restrict__ C_re,  const float* __restrict__ C_im,
                        const float* __restrict__ log_step,
                        const float* __restrict__ ln1_g, const float* __restrict__ ln1_b,
                        const float* __restrict__ D_skip,
                        bf16* __restrict__ Wbu_bf,  // [2][256][128], row 2n=Re 2n+1=Im, g-folded
                        bf16* __restrict__ Wc_bf,   // [2][128][256], col 2n=2Cre 2n+1=-2Cim
                        float* __restrict__ Sb, float* __restrict__ biasb,   // [2][256]
                        float* __restrict__ gd, float* __restrict__ bd,      // [2][128]
                        float4* __restrict__ coefs)
{
    int i = blockIdx.x, n = threadIdx.x;
    int in = i*NST + n;
    float lr = Lam_re[in], li = Lam_im[in];
    float dt = expf(log_step[in]);
    float ea = expf(lr*dt);
    float ar = ea*cosf(li*dt), ai = ea*sinf(li*dt);
    float xx = ar - 1.f, yy = ai;
    float den = lr*lr + li*li;
    float sr = (xx*lr + yy*li)/den;
    float si = (yy*lr - xx*li)/den;
    float2 p = make_float2(ar, ai);
    #pragma unroll
    for (int q = 0; q < 6; ++q) p = cmul2(p, p);   // a^64
    coefs[in] = make_float4(ar, ai, p.x, p.y);

    const float* g  = ln1_g + i*HD;
    const float* bb = ln1_b + i*HD;
    const float* br = B_re + (size_t)in*HD;
    const float* bi = B_im + (size_t)in*HD;
    bf16* wb = Wbu_bf + (size_t)i*256*128;
    float s_re = 0.f, s_im = 0.f, bc_re = 0.f, bc_im = 0.f;
    for (int h = 0; h < HD; ++h) {
        float wre = sr*br[h] - si*bi[h];
        float wim = sr*bi[h] + si*br[h];
        bf16 wrb = f2bf(g[h]*wre), wib = f2bf(g[h]*wim);
        wb[(2*n)*128 + h]   = wrb;
        wb[(2*n+1)*128 + h] = wib;
        s_re += bf2f(wrb); s_im += bf2f(wib);
        bc_re += bb[h]*wre; bc_im += bb[h]*wim;
    }
    Sb[i*256 + 2*n] = s_re;     Sb[i*256 + 2*n+1] = s_im;
    biasb[i*256 + 2*n] = bc_re; biasb[i*256 + 2*n+1] = bc_im;

    const float* cr = C_re + (size_t)i*HD*NST;
    const float* ci = C_im + (size_t)i*HD*NST;
    bf16* wc = Wc_bf + (size_t)i*128*256;
    for (int h = 0; h < HD; ++h) {
        wc[h*256 + 2*n]   = f2bf( 2.f * cr[h*NST + n]);
        wc[h*256 + 2*n+1] = f2bf(-2.f * ci[h*NST + n]);
    }
    gd[i*HD + n] = g[n]*D_skip[i*HD + n];
    bd[i*HD + n] = bb[n]*D_skip[i*HD + n];
}

// W1 -> g2-folded bf16 [f][h] + S1/bias1' (bias1' includes b1)
__global__ void prep_w1(const float* __restrict__ W1, const float* __restrict__ b1,
                        const float* __restrict__ ln2_g, const float* __restrict__ ln2_b,
                        bf16* __restrict__ W1_bf, float* __restrict__ S1,
                        float* __restrict__ bias1p)
{
    int i = blockIdx.x, f = threadIdx.x;       // f in [0,256)
    const float* g  = ln2_g + i*HD;
    const float* bb = ln2_b + i*HD;
    bf16* w = W1_bf + (size_t)i*256*128;
    float S = 0.f, bi_ = b1[i*256 + f];
    for (int h = 0; h < HD; ++h) {
        float wv = W1[(size_t)i*32768 + h*256 + f];
        bf16 wbv = f2bf(g[h]*wv);
        w[f*128 + h] = wbv;
        S += bf2f(wbv);
        bi_ += bb[h]*wv;
    }
    S1[i*256 + f] = S;
    bias1p[i*256 + f] = bi_;
}

// W2 -> plain bf16 transposed [h][f]
__global__ void prep_w2(const float* __restrict__ W2, bf16* __restrict__ W2_bf)
{
    int i = blockIdx.x, h = threadIdx.x;       // h in [0,128)
    bf16* w = W2_bf + (size_t)i*128*256;
    for (int f = 0; f < 256; ++f)
        w[h*256 + f] = f2bf(W2[(size_t)i*32768 + f*128 + h]);
}

// conv weights [c][ic][tap] -> bf16 [c][tap*128+ic]
__global__ void prep_wB(const float* __restrict__ w1, const float* __restrict__ w2,
                        bf16* __restrict__ wB1, bf16* __restrict__ wB2)
{
    int idx = blockIdx.x*256 + threadIdx.x;
    if (idx >= 163840) return;
    const float* w = (idx < 81920) ? w1 : w2;
    bf16* wb       = (idx < 81920) ? wB1 : wB2;
    int r   = idx % 81920;
    int c   = r / 640;
    int tap = (r % 640) / 128;
    int ic  = r % 128;
    wb[r] = f2bf(w[(c*128 + ic)*5 + tap]);
}

// ---------------- fused LN + GEMM (K=128, N=256), bf16 out, persistent waves ----------
// acc on raw bf16(v); LN folded: out_n = rs*acc - mu*rs*S_n + bias_n  [, gelu]
// UD=1: also writes ud = xn*dskip (bf16) and no activation (Bu). UD=0: gelu (h).
template<int UD>
__global__ __launch_bounds__(1024, 4) void lngemm(
    const float* __restrict__ A,       // [BT,128] fp32
    const bf16* __restrict__ Bt,       // [256][128] g-folded
    const float* __restrict__ Svec, const float* __restrict__ bvec,  // [256]
    bf16* __restrict__ outB,           // [BT,256]
    const float* __restrict__ gdp, const float* __restrict__ bdp,    // [128]
    bf16* __restrict__ udout)          // [BT,128]
{
    __shared__ bf16 Bs[256*136];       // 69632 B (+8 pad per row)
    __shared__ float tsp[16*384];      // per-wave 16x24 transpose scratch
    __shared__ float Sl[256], bl[256];
    __shared__ float gdl[128], bdl[128];

    int tid = threadIdx.x;
    #pragma unroll
    for (int it = 0; it < 4; ++it) {
        int f = it*1024 + tid;
        int n = f >> 4, kk = (f & 15)*8;
        *(bf16x8*)&Bs[n*136 + kk] = *(const bf16x8*)(Bt + n*128 + kk);
    }
    if (tid < 256) { Sl[tid] = Svec[tid]; bl[tid] = bvec[tid]; }
    if constexpr (UD) {
        if (tid >= 256 && tid < 384) { gdl[tid-256] = gdp[tid-256]; bdl[tid-256] = bdp[tid-256]; }
    }
    __syncthreads();

    int wid = tid >> 6, lane = tid & 63;
    int quad = lane >> 4, cl = lane & 15;
    int s = blockIdx.x*16 + wid;                  // strip [0,8192)
    size_t row = (size_t)s*16 + cl;
    const float* ar = A + row*128;

    float v[32];
    #pragma unroll
    for (int ks = 0; ks < 4; ++ks) {
        float4 f0 = *(const float4*)(ar + quad*8 + ks*32);
        float4 f1 = *(const float4*)(ar + quad*8 + ks*32 + 4);
        v[ks*8+0]=f0.x; v[ks*8+1]=f0.y; v[ks*8+2]=f0.z; v[ks*8+3]=f0.w;
        v[ks*8+4]=f1.x; v[ks*8+5]=f1.y; v[ks*8+6]=f1.z; v[ks*8+7]=f1.w;
    }
    float sm = 0.f, sq = 0.f;
    #pragma unroll
    for (int j = 0; j < 32; ++j) { sm += v[j]; sq += v[j]*v[j]; }
    sm += __shfl_xor(sm, 16); sm += __shfl_xor(sm, 32);
    sq += __shfl_xor(sq, 16); sq += __shfl_xor(sq, 32);
    float mu = sm * (1.f/128.f);
    float rs = rsqrtf(sq*(1.f/128.f) - mu*mu + 1e-5f);

    bf16x8 af[4];
    #pragma unroll
    for (int ks = 0; ks < 4; ++ks) af[ks] = pack8(&v[ks*8]);

    if constexpr (UD) {
        #pragma unroll
        for (int ks = 0; ks < 4; ++ks) {
            float un[8];
            const float* gq = &gdl[quad*8 + ks*32];
            const float* bq = &bdl[quad*8 + ks*32];
            #pragma unroll
            for (int j = 0; j < 8; ++j) un[j] = (v[ks*8+j] - mu)*rs*gq[j] + bq[j];
            *(bf16x8*)(udout + row*128 + quad*8 + ks*32) = pack8(un);
        }
    }

    float mu_r = __shfl(mu, cl);     // stats for transposed row (= lane cl, quad 0)
    float rs_r = __shfl(rs, cl);
    float mr = mu_r*rs_r;
    float* mytsp = &tsp[wid*384];

    #pragma unroll
    for (int half = 0; half < 2; ++half) {
        f32x4 acc[8] = {};
        #pragma unroll
        for (int nt = 0; nt < 8; ++nt) {
            const bf16* brp = &Bs[((half*8+nt)*16 + cl)*136 + quad*8];
            #pragma unroll
            for (int ks = 0; ks < 4; ++ks)
                acc[nt] = __builtin_amdgcn_mfma_f32_16x16x32_bf16(
                              af[ks], *(const bf16x8*)(brp + ks*32), acc[nt], 0, 0, 0);
        }
        #pragma unroll
        for (int nt = 0; nt < 8; ++nt) {
            #pragma unroll
            for (int r = 0; r < 4; ++r) mytsp[(quad*4+r)*24 + cl] = acc[nt][r];
            __builtin_amdgcn_wave_barrier();
            float4 t = *(const float4*)&mytsp[cl*24 + quad*4];
            __builtin_amdgcn_wave_barrier();
            int n0 = (half*8+nt)*16 + quad*4;
            float4 S4 = *(const float4*)&Sl[n0];
            float4 b4 = *(const float4*)&bl[n0];
            float4 o;
            o.x = rs_r*t.x - mr*S4.x + b4.x;
            o.y = rs_r*t.y - mr*S4.y + b4.y;
            o.z = rs_r*t.z - mr*S4.z + b4.z;
            o.w = rs_r*t.w - mr*S4.w + b4.w;
            if constexpr (!UD) {
                o.x = gelu_f(o.x); o.y = gelu_f(o.y);
                o.z = gelu_f(o.z); o.w = gelu_f(o.w);
            }
            ushort4 pu = make_ushort4(f2bf(o.x), f2bf(o.y), f2bf(o.z), f2bf(o.w));
            *(ushort4*)(outB + ((size_t)s*16 + cl)*256 + n0) = pu;
        }
    }
}

// ---------------- GEMM K=256 N=128 (bf16 A), fp32 out, persistent waves --------------
// EPI: 2 = acc+bias+resid; 3 = resid+acc+ud (ud pre-multiplied by dskip)
template<int EPI>
__global__ __launch_bounds__(1024, 4) void gemm2(
    const bf16* __restrict__ A,        // [BT,256]
    const bf16* __restrict__ Bt,       // [128][256]
    float* out,                        // [BT,128] (may alias resid, same-elem r-then-w)
    const float* __restrict__ bias,
    const float* resid,
    const bf16* __restrict__ ud)
{
    __shared__ bf16 Bs[128*264];       // 67584 B
    __shared__ float tsp[16*384];

    int tid = threadIdx.x;
    #pragma unroll
    for (int it = 0; it < 4; ++it) {
        int f = it*1024 + tid;
        int n = f >> 5, kk = (f & 31)*8;
        *(bf16x8*)&Bs[n*264 + kk] = *(const bf16x8*)(Bt + n*256 + kk);
    }
    __syncthreads();

    int wid = tid >> 6, lane = tid & 63;
    int quad = lane >> 4, cl = lane & 15;
    int s = blockIdx.x*16 + wid;
    size_t row = (size_t)s*16 + cl;

    bf16x8 af[8];
    #pragma unroll
    for (int ks = 0; ks < 8; ++ks)
        af[ks] = *(const bf16x8*)(A + row*256 + quad*8 + ks*32);

    f32x4 acc[8] = {};
    #pragma unroll
    for (int nt = 0; nt < 8; ++nt) {
        const bf16* brp = &Bs[(nt*16 + cl)*264 + quad*8];
        #pragma unroll
        for (int ks = 0; ks < 8; ++ks)
            acc[nt] = __builtin_amdgcn_mfma_f32_16x16x32_bf16(
                          af[ks], *(const bf16x8*)(brp + ks*32), acc[nt], 0, 0, 0);
    }

    float* mytsp = &tsp[wid*384];
    #pragma unroll
    for (int nt = 0; nt < 8; ++nt) {
        #pragma unroll
        for (int r = 0; r < 4; ++r) mytsp[(quad*4+r)*24 + cl] = acc[nt][r];
        __builtin_amdgcn_wave_barrier();
        float4 t = *(const float4*)&mytsp[cl*24 + quad*4];
        __builtin_amdgcn_wave_barrier();
        int n0 = nt*16 + quad*4;
        size_t oidx = ((size_t)s*16 + cl)*128 + n0;
        float4 rv = *(const float4*)(resid + oidx);
        float4 o;
        if (EPI == 2) {
            float4 bv = *(const float4*)(bias + n0);
            o.x = t.x + bv.x + rv.x; o.y = t.y + bv.y + rv.y;
            o.z = t.z + bv.z + rv.z; o.w = t.w + bv.w + rv.w;
        } else {
            ushort4 u4 = *(const ushort4*)(ud + oidx);
            o.x = rv.x + t.x + bf2f(u4.x); o.y = rv.y + t.y + bf2f(u4.y);
            o.z = rv.z + t.z + bf2f(u4.z); o.w = rv.w + t.w + bf2f(u4.w);
        }
        *(float4*)(out + oidx) = o;
    }
}

// ---------------- chunked scan on bf16-pair xs: x_t = a*x_{t-1} + Bu_t ---------------
__global__ __launch_bounds__(256) void scan_local(unsigned int* __restrict__ xs,
                                                  const float4* __restrict__ coefs,
                                                  float2* __restrict__ carry)
{
    int flat = blockIdx.x*256 + threadIdx.x;  // 2^18
    int n = flat & 127;
    int b = (flat >> 7) & 31;
    int c = flat >> 12;
    float4 cf = coefs[n];
    float2 a = make_float2(cf.x, cf.y);
    unsigned int* base = xs + ((size_t)(b*TSEQ + c*LC))*NST + n;
    float2 x = make_float2(0.f, 0.f);
    for (int j = 0; j < LC; ++j) {
        float2 v = upk(base[(size_t)j*NST]);
        x = make_float2(a.x*x.x - a.y*x.y + v.x, a.x*x.y + a.y*x.x + v.y);
        base[(size_t)j*NST] = pk(x);
    }
    carry[c*(BATCH*NST) + b*NST + n] = x;
}

__global__ void scan_carry(float2* __restrict__ carry, const float4* __restrict__ coefs)
{
    int flat = blockIdx.x*256 + threadIdx.x;  // 4096 = B*N
    int n = flat & 127;
    float4 cf = coefs[n];
    float2 aL = make_float2(cf.z, cf.w);
    float2 x = make_float2(0.f, 0.f);
    for (int c = 0; c < NCHK; ++c) {
        float2* p = carry + c*(BATCH*NST) + flat;
        float2 v = *p;
        *p = x;                                // exclusive prefix
        x = make_float2(aL.x*x.x - aL.y*x.y + v.x, aL.x*x.y + aL.y*x.x + v.y);
    }
}

__global__ __launch_bounds__(256) void scan_fix(unsigned int* __restrict__ xs,
                                                const float4* __restrict__ coefs,
                                                const float2* __restrict__ carry)
{
    int flat = blockIdx.x*256 + threadIdx.x;
    int n = flat & 127;
    int b = (flat >> 7) & 31;
    int c = flat >> 12;
    if (c == 0) return;
    float2 cin = carry[c*(BATCH*NST) + b*NST + n];
    float4 cf = coefs[n];
    float2 a = make_float2(cf.x, cf.y);
    unsigned int* base = xs + ((size_t)(b*TSEQ + c*LC))*NST + n;
    float2 p = a;
    for (int j = 0; j < LC; ++j) {
        float2 add = cmul2(p, cin);
        float2 v = upk(base[(size_t)j*NST]);
        base[(size_t)j*NST] = pk(make_float2(v.x + add.x, v.y + add.y));
        p = cmul2(p, a);
    }
}

// ---------------- conv1: fp32 in, implicit-im2col MFMA, bf16 out + relu --------------
__global__ __launch_bounds__(256, 3) void conv1_mfma(
    const float* __restrict__ X,
    const bf16* __restrict__ wB,    // [128][640]
    const float* __restrict__ bias,
    bf16* __restrict__ out,         // [B*Lout][128]
    int Tin, int Lout)
{
    __shared__ bf16 As[128][72];
    __shared__ bf16 Bs[128][72];
    __shared__ float tsp[4*384];
    int tid  = threadIdx.x;
    int lane = tid & 63;
    int wave = tid >> 6;
    int wm = wave >> 1, wn = wave & 1;
    int quad = lane >> 4, cl = lane & 15;
    int row0 = blockIdx.x * 128;
    int b  = row0 / Lout;
    int l0 = row0 % Lout;
    const float* Xb = X + (size_t)b*Tin*128;

    f32x4 acc[4][4] = {};

    for (int k0 = 0; k0 < 640; k0 += 64) {
        int tap = k0 / 128;
        int icb = k0 % 128;
        #pragma unroll
        for (int it = 0; it < 8; ++it) {
            int idx = it*256 + tid;
            int r = idx >> 4, kof = (idx & 15) * 4;
            int t = 2*(l0 + r) - 2 + tap;
            ushort4 h = make_ushort4(0,0,0,0);
            if (t >= 0 && t < Tin) {
                float4 f = *(const float4*)(Xb + (size_t)t*128 + icb + kof);
                h.x = f2bf(f.x); h.y = f2bf(f.y); h.z = f2bf(f.z); h.w = f2bf(f.w);
            }
            *(ushort4*)&As[r][kof] = h;
        }
        #pragma unroll
        for (int it = 0; it < 4; ++it) {
            int idx = it*256 + tid;
            int n = idx >> 3, kof = (idx & 7) * 8;
            *(bf16x8*)&Bs[n][kof] = *(const bf16x8*)(wB + (size_t)n*640 + k0 + kof);
        }
        __syncthreads();
        #pragma unroll
        for (int kk = 0; kk < 64; kk += 32) {
            bf16x8 af[4], bfr[4];
            #pragma unroll
            for (int i = 0; i < 4; ++i)
                af[i] = *(const bf16x8*)&As[wm*64 + i*16 + cl][kk + quad*8];
            #pragma unroll
            for (int j = 0; j < 4; ++j)
                bfr[j] = *(const bf16x8*)&Bs[wn*64 + j*16 + cl][kk + quad*8];
            #pragma unroll
            for (int i = 0; i < 4; ++i)
                #pragma unroll
                for (int j = 0; j < 4; ++j)
                    acc[i][j] = __builtin_amdgcn_mfma_f32_16x16x32_bf16(
                                    af[i], bfr[j], acc[i][j], 0, 0, 0);
        }
        __syncthreads();
    }

    float* mytsp = &tsp[wave*384];
    #pragma unroll
    for (int i = 0; i < 4; ++i) {
        #pragma unroll
        for (int j = 0; j < 4; ++j) {
            #pragma unroll
            for (int r = 0; r < 4; ++r) mytsp[(quad*4+r)*24 + cl] = acc[i][j][r];
            __builtin_amdgcn_wave_barrier();
            float4 t = *(const float4*)&mytsp[cl*24 + quad*4];
            __builtin_amdgcn_wave_barrier();
            int gcol = wn*64 + j*16 + quad*4;
            float4 bv = *(const float4*)(bias + gcol);
            t.x = fmaxf(t.x + bv.x, 0.f); t.y = fmaxf(t.y + bv.y, 0.f);
            t.z = fmaxf(t.z + bv.z, 0.f); t.w = fmaxf(t.w + bv.w, 0.f);
            ushort4 pu = make_ushort4(f2bf(t.x), f2bf(t.y), f2bf(t.z), f2bf(t.w));
            int grow = row0 + wm*64 + i*16 + cl;
            *(ushort4*)(out + (size_t)grow*128 + gcol) = pu;
        }
    }
}

// ---------------- conv2 (bf16 in) + fused relu + adaptive avg pool -> d_out ----------
// pool window = 16 output positions = one (wm,i) row-group; cross-quad shfl reduce.
__global__ __launch_bounds__(256, 3) void conv2_pool(
    const bf16* __restrict__ X,     // [B][Tin][128]
    const bf16* __restrict__ wB,    // [128][640]
    const float* __restrict__ bias,
    float* __restrict__ outp,       // [B][128][64]
    int Tin, int Lout)
{
    __shared__ bf16 As[128][72];
    __shared__ bf16 Bs[128][72];
    int tid  = threadIdx.x;
    int lane = tid & 63;
    int wave = tid >> 6;
    int wm = wave >> 1, wn = wave & 1;
    int quad = lane >> 4, cl = lane & 15;
    int row0 = blockIdx.x * 128;
    int b  = row0 / Lout;
    int l0 = row0 % Lout;
    int d0 = l0 / 16;
    const bf16* Xb = X + (size_t)b*Tin*128;

    f32x4 acc[4][4] = {};

    for (int k0 = 0; k0 < 640; k0 += 64) {
        int tap = k0 / 128;
        int icb = k0 % 128;
        #pragma unroll
        for (int it = 0; it < 4; ++it) {
            int idx = it*256 + tid;
            int r = idx >> 3, kof = (idx & 7) * 8;
            int t = 2*(l0 + r) - 2 + tap;
            bf16x8 z = {0,0,0,0,0,0,0,0};
            if (t >= 0 && t < Tin) z = *(const bf16x8*)(Xb + (size_t)t*128 + icb + kof);
            *(bf16x8*)&As[r][kof] = z;
        }
        #pragma unroll
        for (int it = 0; it < 4; ++it) {
            int idx = it*256 + tid;
            int n = idx >> 3, kof = (idx & 7) * 8;
            *(bf16x8*)&Bs[n][kof] = *(const bf16x8*)(wB + (size_t)n*640 + k0 + kof);
        }
        __syncthreads();
        #pragma unroll
        for (int kk = 0; kk < 64; kk += 32) {
            bf16x8 af[4], bfr[4];
            #pragma unroll
            for (int i = 0; i < 4; ++i)
                af[i] = *(const bf16x8*)&As[wm*64 + i*16 + cl][kk + quad*8];
            #pragma unroll
            for (int j = 0; j < 4; ++j)
                bfr[j] = *(const bf16x8*)&Bs[wn*64 + j*16 + cl][kk + quad*8];
            #pragma unroll
            for (int i = 0; i < 4; ++i)
                #pragma unroll
                for (int j = 0; j < 4; ++j)
                    acc[i][j] = __builtin_amdgcn_mfma_f32_16x16x32_bf16(
                                    af[i], bfr[j], acc[i][j], 0, 0, 0);
        }
        __syncthreads();
    }

    #pragma unroll
    for (int j = 0; j < 4; ++j) {
        int gcol = wn*64 + j*16 + cl;
        float bv = bias[gcol];
        #pragma unroll
        for (int i = 0; i < 4; ++i) {
            float sp = 0.f;
            #pragma unroll
            for (int r = 0; r < 4; ++r) sp += fmaxf(acc[i][j][r] + bv, 0.f);
            sp += __shfl_xor(sp, 16);
            sp += __shfl_xor(sp, 32);
            if (quad == 0) {
                int d = d0 + wm*4 + i;
                outp[(size_t)b*8192 + gcol*64 + d] = sp * (1.f/16.f);
            }
        }
    }
}

extern "C" void kernel_launch(void* const* d_in, const int* in_sizes, int n_in,
                              void* d_out, int out_size, void* d_ws, size_t ws_size,
                              hipStream_t stream)
{
    (void)in_sizes; (void)n_in; (void)out_size; (void)ws_size;
    const float* x_in    = (const float*)d_in[0];
    const float* ln1_g   = (const float*)d_in[1];
    const float* ln1_b   = (const float*)d_in[2];
    const float* ln2_g   = (const float*)d_in[3];
    const float* ln2_b   = (const float*)d_in[4];
    const float* Lam_re  = (const float*)d_in[5];
    const float* Lam_im  = (const float*)d_in[6];
    const float* B_re    = (const float*)d_in[7];
    const float* B_im    = (const float*)d_in[8];
    const float* C_re    = (const float*)d_in[9];
    const float* C_im    = (const float*)d_in[10];
    const float* D_skip  = (const float*)d_in[11];
    const float* log_step= (const float*)d_in[12];
    const float* W1      = (const float*)d_in[13];
    const float* b1      = (const float*)d_in[14];
    const float* W2      = (const float*)d_in[15];
    const float* b2      = (const float*)d_in[16];
    const float* conv1_w = (const float*)d_in[17];
    const float* conv1_b = (const float*)d_in[18];
    const float* conv2_w = (const float*)d_in[19];
    const float* conv2_b = (const float*)d_in[20];
    float* out = (float*)d_out;

    // Workspace (~188 MB): X fp32 64MB | Cbuf bf16 [BT,256] 64MB | Abf(ud) bf16 32MB
    //                      | conv1out bf16 16MB | params+carry ~3MB
    char* ws = (char*)d_ws;
    float* X      = (float*)(ws);
    bf16*  Cbuf   = (bf16*) (ws + (size_t)67108864);
    bf16*  Abf    = (bf16*) (ws + (size_t)134217728);
    bf16*  Cv1    = (bf16*) (ws + (size_t)167772160);
    char*  wreg   = ws + (size_t)184549376;
    bf16*   Wbu_bf = (bf16*)(wreg);                  // 131072
    bf16*   Wc_bf  = (bf16*)(wreg + 131072);         // 131072
    bf16*   W1_bf  = (bf16*)(wreg + 262144);         // 131072
    bf16*   W2_bf  = (bf16*)(wreg + 393216);         // 131072
    float*  Sb     = (float*)(wreg + 524288);        // 2048
    float*  biasb  = (float*)(wreg + 526336);        // 2048
    float*  S1     = (float*)(wreg + 528384);        // 2048
    float*  bias1p = (float*)(wreg + 530432);        // 2048
    float*  gd     = (float*)(wreg + 532480);        // 1024
    float*  bd     = (float*)(wreg + 533504);        // 1024
    float4* coefs  = (float4*)(wreg + 534528);       // 4096
    bf16*   wB1    = (bf16*)(wreg + 538624);         // 163840
    bf16*   wB2    = (bf16*)(wreg + 702464);         // 163840
    float2* carry  = (float2*)(wreg + 866304);       // 2 MB

    prep_s5<<<2, 128, 0, stream>>>(Lam_re, Lam_im, B_re, B_im, C_re, C_im, log_step,
                                   ln1_g, ln1_b, D_skip,
                                   Wbu_bf, Wc_bf, Sb, biasb, gd, bd, coefs);
    prep_w1<<<2, 256, 0, stream>>>(W1, b1, ln2_g, ln2_b, W1_bf, S1, bias1p);
    prep_w2<<<2, 128, 0, stream>>>(W2, W2_bf);
    prep_wB<<<640, 256, 0, stream>>>(conv1_w, conv2_w, wB1, wB2);

    for (int i = 0; i < 2; ++i) {
        const float* src = (i == 0) ? x_in : X;     // layer input / residual
        // ---- S5 sub-block: fused LN+Wbu (writes Bu + ud), scan, Wc+resid+ud ----
        lngemm<1><<<512, 1024, 0, stream>>>(
            src, Wbu_bf + (size_t)i*32768, Sb + i*256, biasb + i*256,
            Cbuf, gd + i*128, bd + i*128, Abf);
        scan_local<<<1024, 256, 0, stream>>>((unsigned int*)Cbuf, coefs + i*NST, carry);
        scan_carry<<<16, 256, 0, stream>>>(carry, coefs + i*NST);
        scan_fix<<<1024, 256, 0, stream>>>((unsigned int*)Cbuf, coefs + i*NST, carry);
        gemm2<3><<<512, 1024, 0, stream>>>(
            Cbuf, Wc_bf + (size_t)i*32768, X, nullptr, src, Abf);
        // ---- MLP sub-block: fused LN+W1+gelu, W2+bias+resid ----
        lngemm<0><<<512, 1024, 0, stream>>>(
            X, W1_bf + (size_t)i*32768, S1 + i*256, bias1p + i*256,
            Cbuf, nullptr, nullptr, nullptr);
        gemm2<2><<<512, 1024, 0, stream>>>(
            Cbuf, W2_bf + (size_t)i*32768, X, b2 + i*HD, X, nullptr);
    }

    // ---- head: conv1 (X -> bf16) -> conv2+pool (-> d_out) ----
    conv1_mfma<<<512, 256, 0, stream>>>(X, wB1, conv1_b, Cv1, 4096, 2048);
    conv2_pool<<<256, 256, 0, stream>>>(Cv1, wB2, conv2_b, out, 2048, 1024);
}

// Round 7
// 694.943 us; speedup vs baseline: 1.4857x; 1.0322x over previous
//
#include <hip/hip_runtime.h>
#include <math.h>

#define BATCH 32
#define TSEQ  4096
#define HD    128
#define NST   128
#define BT    (BATCH*TSEQ)     // 131072
#define LC    64               // scan chunk length
#define NCHK  (TSEQ/LC)        // 64 chunks

typedef unsigned short bf16;
typedef __attribute__((ext_vector_type(8))) short bf16x8;   // 8 bf16 = 4 VGPRs (MFMA A/B frag)
typedef __attribute__((ext_vector_type(4))) float f32x4;    // MFMA C/D frag

__device__ inline float bf2f(bf16 s) {
    union { unsigned int u; float f; } v; v.u = ((unsigned int)s) << 16; return v.f;
}
__device__ inline bf16 f2bf(float f) {
    union { float f; unsigned int u; } v; v.f = f;
    unsigned int u = v.u;
    unsigned int r = (u + 0x7fffu + ((u >> 16) & 1u)) >> 16;
    return (bf16)r;
}
// pack two f32 -> bf16 pair (round-half-up) in ~3 VALU via v_perm
__device__ inline unsigned int pkpair(float lo, float hi) {
    union { float f; unsigned int u; } a, b;
    a.f = lo; b.f = hi;
    return __builtin_amdgcn_perm(b.u + 0x8000u, a.u + 0x8000u, 0x07060302u);
}
__device__ inline bf16x8 pack8(const float* f) {
    union { bf16x8 v; unsigned int u[4]; } t;
    t.u[0] = pkpair(f[0], f[1]);
    t.u[1] = pkpair(f[2], f[3]);
    t.u[2] = pkpair(f[4], f[5]);
    t.u[3] = pkpair(f[6], f[7]);
    return t.v;
}
__device__ inline float2 cmul2(float2 a, float2 b) {
    return make_float2(a.x*b.x - a.y*b.y, a.x*b.y + a.y*b.x);
}
// tanh-form gelu: max |diff vs exact erf-gelu| ~1e-3, well under bf16 noise here
__device__ inline float gelu_f(float x) {
    float u = x*(0.7978845608f + 0.0356774081f*x*x);
    return __fdividef(x, 1.f + __expf(-2.f*u));
}
__device__ inline float2 upk(unsigned int w) {     // bf16 pair -> fp32 pair
    union { unsigned int u; float f; } a, b;
    a.u = w << 16; b.u = w & 0xffff0000u;
    return make_float2(a.f, b.f);
}
__device__ inline unsigned int pk(float2 x) { return pkpair(x.x, x.y); }

// ---------------- S5 param prep: g-folded W'bu, S/bias corrections, Wc, gd/bd, coefs ----
__global__ void prep_s5(const float* __restrict__ Lam_re, const float* __restrict__ Lam_im,
                        const float* __restrict__ B_re,  const float* __restrict__ B_im,
                        const float* __restrict__ C_re,  const float* __restrict__ C_im,
                        const float* __restrict__ log_step,
                        const float* __restrict__ ln1_g, const float* __restrict__ ln1_b,
                        const float* __restrict__ D_skip,
                        bf16* __restrict__ Wbu_bf,  // [2][256][128], row 2n=Re 2n+1=Im, g-folded
                        bf16* __restrict__ Wc_bf,   // [2][128][256], col 2n=2Cre 2n+1=-2Cim
                        float* __restrict__ Sb, float* __restrict__ biasb,   // [2][256]
                        float* __restrict__ gd, float* __restrict__ bd,      // [2][128]
                        float4* __restrict__ coefs)
{
    int i = blockIdx.x, n = threadIdx.x;
    int in = i*NST + n;
    float lr = Lam_re[in], li = Lam_im[in];
    float dt = expf(log_step[in]);
    float ea = expf(lr*dt);
    float ar = ea*cosf(li*dt), ai = ea*sinf(li*dt);
    float xx = ar - 1.f, yy = ai;
    float den = lr*lr + li*li;
    float sr = (xx*lr + yy*li)/den;
    float si = (yy*lr - xx*li)/den;
    float2 p = make_float2(ar, ai);
    #pragma unroll
    for (int q = 0; q < 6; ++q) p = cmul2(p, p);   // a^64
    coefs[in] = make_float4(ar, ai, p.x, p.y);

    const float* g  = ln1_g + i*HD;
    const float* bb = ln1_b + i*HD;
    const float* br = B_re + (size_t)in*HD;
    const float* bi = B_im + (size_t)in*HD;
    bf16* wb = Wbu_bf + (size_t)i*256*128;
    float s_re = 0.f, s_im = 0.f, bc_re = 0.f, bc_im = 0.f;
    for (int h = 0; h < HD; ++h) {
        float wre = sr*br[h] - si*bi[h];
        float wim = sr*bi[h] + si*br[h];
        bf16 wrb = f2bf(g[h]*wre), wib = f2bf(g[h]*wim);
        wb[(2*n)*128 + h]   = wrb;
        wb[(2*n+1)*128 + h] = wib;
        s_re += bf2f(wrb); s_im += bf2f(wib);
        bc_re += bb[h]*wre; bc_im += bb[h]*wim;
    }
    Sb[i*256 + 2*n] = s_re;     Sb[i*256 + 2*n+1] = s_im;
    biasb[i*256 + 2*n] = bc_re; biasb[i*256 + 2*n+1] = bc_im;

    const float* cr = C_re + (size_t)i*HD*NST;
    const float* ci = C_im + (size_t)i*HD*NST;
    bf16* wc = Wc_bf + (size_t)i*128*256;
    for (int h = 0; h < HD; ++h) {
        wc[h*256 + 2*n]   = f2bf( 2.f * cr[h*NST + n]);
        wc[h*256 + 2*n+1] = f2bf(-2.f * ci[h*NST + n]);
    }
    gd[i*HD + n] = g[n]*D_skip[i*HD + n];
    bd[i*HD + n] = bb[n]*D_skip[i*HD + n];
}

// W1 -> g2-folded bf16 [f][h] + S1/bias1' (bias1' includes b1)
__global__ void prep_w1(const float* __restrict__ W1, const float* __restrict__ b1,
                        const float* __restrict__ ln2_g, const float* __restrict__ ln2_b,
                        bf16* __restrict__ W1_bf, float* __restrict__ S1,
                        float* __restrict__ bias1p)
{
    int i = blockIdx.x, f = threadIdx.x;       // f in [0,256)
    const float* g  = ln2_g + i*HD;
    const float* bb = ln2_b + i*HD;
    bf16* w = W1_bf + (size_t)i*256*128;
    float S = 0.f, bi_ = b1[i*256 + f];
    for (int h = 0; h < HD; ++h) {
        float wv = W1[(size_t)i*32768 + h*256 + f];
        bf16 wbv = f2bf(g[h]*wv);
        w[f*128 + h] = wbv;
        S += bf2f(wbv);
        bi_ += bb[h]*wv;
    }
    S1[i*256 + f] = S;
    bias1p[i*256 + f] = bi_;
}

// W2 -> plain bf16 transposed [h][f]
__global__ void prep_w2(const float* __restrict__ W2, bf16* __restrict__ W2_bf)
{
    int i = blockIdx.x, h = threadIdx.x;       // h in [0,128)
    bf16* w = W2_bf + (size_t)i*128*256;
    for (int f = 0; f < 256; ++f)
        w[h*256 + f] = f2bf(W2[(size_t)i*32768 + f*128 + h]);
}

// conv weights [c][ic][tap] -> bf16 [c][tap*128+ic]
__global__ void prep_wB(const float* __restrict__ w1, const float* __restrict__ w2,
                        bf16* __restrict__ wB1, bf16* __restrict__ wB2)
{
    int idx = blockIdx.x*256 + threadIdx.x;
    if (idx >= 163840) return;
    const float* w = (idx < 81920) ? w1 : w2;
    bf16* wb       = (idx < 81920) ? wB1 : wB2;
    int r   = idx % 81920;
    int c   = r / 640;
    int tap = (r % 640) / 128;
    int ic  = r % 128;
    wb[r] = f2bf(w[(c*128 + ic)*5 + tap]);
}

// ---------------- fused LN + GEMM (K=128, N=256), bf16 out, persistent waves ----------
// acc on raw bf16(v); LN folded: out_n = rs*acc - mu*rs*S_n + bias_n  [, gelu]
// UD=1: also writes ud = xn*dskip (bf16) and no activation (Bu). UD=0: gelu (h).
template<int UD>
__global__ __launch_bounds__(1024, 4) void lngemm(
    const float* __restrict__ A,       // [BT,128] fp32
    const bf16* __restrict__ Bt,       // [256][128] g-folded
    const float* __restrict__ Svec, const float* __restrict__ bvec,  // [256]
    bf16* __restrict__ outB,           // [BT,256]
    const float* __restrict__ gdp, const float* __restrict__ bdp,    // [128]
    bf16* __restrict__ udout)          // [BT,128]
{
    __shared__ bf16 Bs[256*136];       // 69632 B (+8 pad per row)
    __shared__ float tsp[16*320];      // per-wave 16x16 transpose scratch, stride 20
    __shared__ float Sl[256], bl[256];
    __shared__ float gdl[128], bdl[128];

    int tid = threadIdx.x;
    #pragma unroll
    for (int it = 0; it < 4; ++it) {
        int f = it*1024 + tid;
        int n = f >> 4, kk = (f & 15)*8;
        *(bf16x8*)&Bs[n*136 + kk] = *(const bf16x8*)(Bt + n*128 + kk);
    }
    if (tid < 256) { Sl[tid] = Svec[tid]; bl[tid] = bvec[tid]; }
    if constexpr (UD) {
        if (tid >= 256 && tid < 384) { gdl[tid-256] = gdp[tid-256]; bdl[tid-256] = bdp[tid-256]; }
    }
    __syncthreads();

    int wid = tid >> 6, lane = tid & 63;
    int quad = lane >> 4, cl = lane & 15;
    int s = blockIdx.x*16 + wid;                  // strip [0,8192)
    size_t row = (size_t)s*16 + cl;
    const float* ar = A + row*128;

    float v[32];
    #pragma unroll
    for (int ks = 0; ks < 4; ++ks) {
        float4 f0 = *(const float4*)(ar + quad*8 + ks*32);
        float4 f1 = *(const float4*)(ar + quad*8 + ks*32 + 4);
        v[ks*8+0]=f0.x; v[ks*8+1]=f0.y; v[ks*8+2]=f0.z; v[ks*8+3]=f0.w;
        v[ks*8+4]=f1.x; v[ks*8+5]=f1.y; v[ks*8+6]=f1.z; v[ks*8+7]=f1.w;
    }
    float sm = 0.f, sq = 0.f;
    #pragma unroll
    for (int j = 0; j < 32; ++j) { sm += v[j]; sq += v[j]*v[j]; }
    sm += __shfl_xor(sm, 16); sm += __shfl_xor(sm, 32);
    sq += __shfl_xor(sq, 16); sq += __shfl_xor(sq, 32);
    float mu = sm * (1.f/128.f);
    float rs = rsqrtf(sq*(1.f/128.f) - mu*mu + 1e-5f);

    bf16x8 af[4];
    #pragma unroll
    for (int ks = 0; ks < 4; ++ks) af[ks] = pack8(&v[ks*8]);

    if constexpr (UD) {
        #pragma unroll
        for (int ks = 0; ks < 4; ++ks) {
            float un[8];
            const float* gq = &gdl[quad*8 + ks*32];
            const float* bq = &bdl[quad*8 + ks*32];
            #pragma unroll
            for (int j = 0; j < 8; ++j) un[j] = (v[ks*8+j] - mu)*rs*gq[j] + bq[j];
            *(bf16x8*)(udout + row*128 + quad*8 + ks*32) = pack8(un);
        }
    }

    float mu_r = __shfl(mu, cl);     // stats for transposed row (= lane cl, quad 0)
    float rs_r = __shfl(rs, cl);
    float mr = mu_r*rs_r;
    float* mytsp = &tsp[wid*320];

    #pragma unroll
    for (int half = 0; half < 2; ++half) {
        f32x4 acc[8] = {};
        #pragma unroll
        for (int nt = 0; nt < 8; ++nt) {
            const bf16* brp = &Bs[((half*8+nt)*16 + cl)*136 + quad*8];
            #pragma unroll
            for (int ks = 0; ks < 4; ++ks)
                acc[nt] = __builtin_amdgcn_mfma_f32_16x16x32_bf16(
                              af[ks], *(const bf16x8*)(brp + ks*32), acc[nt], 0, 0, 0);
        }
        #pragma unroll
        for (int nt = 0; nt < 8; ++nt) {
            #pragma unroll
            for (int r = 0; r < 4; ++r) mytsp[(quad*4+r)*20 + cl] = acc[nt][r];
            __builtin_amdgcn_wave_barrier();
            float4 t = *(const float4*)&mytsp[cl*20 + quad*4];
            __builtin_amdgcn_wave_barrier();
            int n0 = (half*8+nt)*16 + quad*4;
            float4 S4 = *(const float4*)&Sl[n0];
            float4 b4 = *(const float4*)&bl[n0];
            float4 o;
            o.x = rs_r*t.x - mr*S4.x + b4.x;
            o.y = rs_r*t.y - mr*S4.y + b4.y;
            o.z = rs_r*t.z - mr*S4.z + b4.z;
            o.w = rs_r*t.w - mr*S4.w + b4.w;
            if constexpr (!UD) {
                o.x = gelu_f(o.x); o.y = gelu_f(o.y);
                o.z = gelu_f(o.z); o.w = gelu_f(o.w);
            }
            uint2 pu = make_uint2(pkpair(o.x, o.y), pkpair(o.z, o.w));
            *(uint2*)(outB + ((size_t)s*16 + cl)*256 + n0) = pu;
        }
    }
}

// ---------------- GEMM K=256 N=128 (bf16 A), fp32 out, persistent waves --------------
// EPI: 2 = acc+bias+resid; 3 = resid+acc+ud (ud pre-multiplied by dskip)
template<int EPI>
__global__ __launch_bounds__(1024, 4) void gemm2(
    const bf16* __restrict__ A,        // [BT,256]
    const bf16* __restrict__ Bt,       // [128][256]
    float* out,                        // [BT,128] (may alias resid, same-elem r-then-w)
    const float* __restrict__ bias,
    const float* resid,
    const bf16* __restrict__ ud)
{
    __shared__ bf16 Bs[128*264];       // 67584 B
    __shared__ float tsp[16*320];

    int tid = threadIdx.x;
    #pragma unroll
    for (int it = 0; it < 4; ++it) {
        int f = it*1024 + tid;
        int n = f >> 5, kk = (f & 31)*8;
        *(bf16x8*)&Bs[n*264 + kk] = *(const bf16x8*)(Bt + n*256 + kk);
    }
    __syncthreads();

    int wid = tid >> 6, lane = tid & 63;
    int quad = lane >> 4, cl = lane & 15;
    int s = blockIdx.x*16 + wid;
    size_t row = (size_t)s*16 + cl;

    bf16x8 af[8];
    #pragma unroll
    for (int ks = 0; ks < 8; ++ks)
        af[ks] = *(const bf16x8*)(A + row*256 + quad*8 + ks*32);

    f32x4 acc[8] = {};
    #pragma unroll
    for (int nt = 0; nt < 8; ++nt) {
        const bf16* brp = &Bs[(nt*16 + cl)*264 + quad*8];
        #pragma unroll
        for (int ks = 0; ks < 8; ++ks)
            acc[nt] = __builtin_amdgcn_mfma_f32_16x16x32_bf16(
                          af[ks], *(const bf16x8*)(brp + ks*32), acc[nt], 0, 0, 0);
    }

    float* mytsp = &tsp[wid*320];
    #pragma unroll
    for (int nt = 0; nt < 8; ++nt) {
        #pragma unroll
        for (int r = 0; r < 4; ++r) mytsp[(quad*4+r)*20 + cl] = acc[nt][r];
        __builtin_amdgcn_wave_barrier();
        float4 t = *(const float4*)&mytsp[cl*20 + quad*4];
        __builtin_amdgcn_wave_barrier();
        int n0 = nt*16 + quad*4;
        size_t oidx = ((size_t)s*16 + cl)*128 + n0;
        float4 rv = *(const float4*)(resid + oidx);
        float4 o;
        if (EPI == 2) {
            float4 bv = *(const float4*)(bias + n0);
            o.x = t.x + bv.x + rv.x; o.y = t.y + bv.y + rv.y;
            o.z = t.z + bv.z + rv.z; o.w = t.w + bv.w + rv.w;
        } else {
            ushort4 u4 = *(const ushort4*)(ud + oidx);
            o.x = rv.x + t.x + bf2f(u4.x); o.y = rv.y + t.y + bf2f(u4.y);
            o.z = rv.z + t.z + bf2f(u4.z); o.w = rv.w + t.w + bf2f(u4.w);
        }
        *(float4*)(out + oidx) = o;
    }
}

// ---------------- chunked scan on bf16-pair xs: x_t = a*x_{t-1} + Bu_t ---------------
__global__ __launch_bounds__(256) void scan_local(unsigned int* __restrict__ xs,
                                                  const float4* __restrict__ coefs,
                                                  float2* __restrict__ carry)
{
    int flat = blockIdx.x*256 + threadIdx.x;  // 2^18
    int n = flat & 127;
    int b = (flat >> 7) & 31;
    int c = flat >> 12;
    float4 cf = coefs[n];
    float2 a = make_float2(cf.x, cf.y);
    unsigned int* base = xs + ((size_t)(b*TSEQ + c*LC))*NST + n;
    float2 x = make_float2(0.f, 0.f);
    for (int j = 0; j < LC; ++j) {
        float2 v = upk(base[(size_t)j*NST]);
        x = make_float2(a.x*x.x - a.y*x.y + v.x, a.x*x.y + a.y*x.x + v.y);
        base[(size_t)j*NST] = pk(x);
    }
    carry[c*(BATCH*NST) + b*NST + n] = x;
}

__global__ void scan_carry(float2* __restrict__ carry, const float4* __restrict__ coefs)
{
    int flat = blockIdx.x*256 + threadIdx.x;  // 4096 = B*N
    int n = flat & 127;
    float4 cf = coefs[n];
    float2 aL = make_float2(cf.z, cf.w);
    float2 x = make_float2(0.f, 0.f);
    for (int c = 0; c < NCHK; ++c) {
        float2* p = carry + c*(BATCH*NST) + flat;
        float2 v = *p;
        *p = x;                                // exclusive prefix
        x = make_float2(aL.x*x.x - aL.y*x.y + v.x, aL.x*x.y + aL.y*x.x + v.y);
    }
}

__global__ __launch_bounds__(256) void scan_fix(unsigned int* __restrict__ xs,
                                                const float4* __restrict__ coefs,
                                                const float2* __restrict__ carry)
{
    int flat = blockIdx.x*256 + threadIdx.x;
    int n = flat & 127;
    int b = (flat >> 7) & 31;
    int c = flat >> 12;
    if (c == 0) return;
    float2 cin = carry[c*(BATCH*NST) + b*NST + n];
    float4 cf = coefs[n];
    float2 a = make_float2(cf.x, cf.y);
    unsigned int* base = xs + ((size_t)(b*TSEQ + c*LC))*NST + n;
    float2 p = a;
    for (int j = 0; j < LC; ++j) {
        float2 add = cmul2(p, cin);
        float2 v = upk(base[(size_t)j*NST]);
        base[(size_t)j*NST] = pk(make_float2(v.x + add.x, v.y + add.y));
        p = cmul2(p, a);
    }
}

// ---------------- conv1: fp32 in, implicit-im2col MFMA, bf16 out + relu --------------
__global__ __launch_bounds__(256, 3) void conv1_mfma(
    const float* __restrict__ X,
    const bf16* __restrict__ wB,    // [128][640]
    const float* __restrict__ bias,
    bf16* __restrict__ out,         // [B*Lout][128]
    int Tin, int Lout)
{
    __shared__ bf16 As[128][72];
    __shared__ bf16 Bs[128][72];
    __shared__ float tsp[4*320];
    int tid  = threadIdx.x;
    int lane = tid & 63;
    int wave = tid >> 6;
    int wm = wave >> 1, wn = wave & 1;
    int quad = lane >> 4, cl = lane & 15;
    int row0 = blockIdx.x * 128;
    int b  = row0 / Lout;
    int l0 = row0 % Lout;
    const float* Xb = X + (size_t)b*Tin*128;

    f32x4 acc[4][4] = {};

    for (int k0 = 0; k0 < 640; k0 += 64) {
        int tap = k0 / 128;
        int icb = k0 % 128;
        #pragma unroll
        for (int it = 0; it < 8; ++it) {
            int idx = it*256 + tid;
            int r = idx >> 4, kof = (idx & 15) * 4;
            int t = 2*(l0 + r) - 2 + tap;
            uint2 h = make_uint2(0u, 0u);
            if (t >= 0 && t < Tin) {
                float4 f = *(const float4*)(Xb + (size_t)t*128 + icb + kof);
                h = make_uint2(pkpair(f.x, f.y), pkpair(f.z, f.w));
            }
            *(uint2*)&As[r][kof] = h;
        }
        #pragma unroll
        for (int it = 0; it < 4; ++it) {
            int idx = it*256 + tid;
            int n = idx >> 3, kof = (idx & 7) * 8;
            *(bf16x8*)&Bs[n][kof] = *(const bf16x8*)(wB + (size_t)n*640 + k0 + kof);
        }
        __syncthreads();
        #pragma unroll
        for (int kk = 0; kk < 64; kk += 32) {
            bf16x8 af[4], bfr[4];
            #pragma unroll
            for (int i = 0; i < 4; ++i)
                af[i] = *(const bf16x8*)&As[wm*64 + i*16 + cl][kk + quad*8];
            #pragma unroll
            for (int j = 0; j < 4; ++j)
                bfr[j] = *(const bf16x8*)&Bs[wn*64 + j*16 + cl][kk + quad*8];
            #pragma unroll
            for (int i = 0; i < 4; ++i)
                #pragma unroll
                for (int j = 0; j < 4; ++j)
                    acc[i][j] = __builtin_amdgcn_mfma_f32_16x16x32_bf16(
                                    af[i], bfr[j], acc[i][j], 0, 0, 0);
        }
        __syncthreads();
    }

    float* mytsp = &tsp[wave*320];
    #pragma unroll
    for (int i = 0; i < 4; ++i) {
        #pragma unroll
        for (int j = 0; j < 4; ++j) {
            #pragma unroll
            for (int r = 0; r < 4; ++r) mytsp[(quad*4+r)*20 + cl] = acc[i][j][r];
            __builtin_amdgcn_wave_barrier();
            float4 t = *(const float4*)&mytsp[cl*20 + quad*4];
            __builtin_amdgcn_wave_barrier();
            int gcol = wn*64 + j*16 + quad*4;
            float4 bv = *(const float4*)(bias + gcol);
            t.x = fmaxf(t.x + bv.x, 0.f); t.y = fmaxf(t.y + bv.y, 0.f);
            t.z = fmaxf(t.z + bv.z, 0.f); t.w = fmaxf(t.w + bv.w, 0.f);
            uint2 pu = make_uint2(pkpair(t.x, t.y), pkpair(t.z, t.w));
            int grow = row0 + wm*64 + i*16 + cl;
            *(uint2*)(out + (size_t)grow*128 + gcol) = pu;
        }
    }
}

// ---------------- conv2 (bf16 in) + fused relu + adaptive avg pool -> d_out ----------
// pool window = 16 output positions = one (wm,i) row-group; cross-quad shfl reduce.
__global__ __launch_bounds__(256, 3) void conv2_pool(
    const bf16* __restrict__ X,     // [B][Tin][128]
    const bf16* __restrict__ wB,    // [128][640]
    const float* __restrict__ bias,
    float* __restrict__ outp,       // [B][128][64]
    int Tin, int Lout)
{
    __shared__ bf16 As[128][72];
    __shared__ bf16 Bs[128][72];
    int tid  = threadIdx.x;
    int lane = tid & 63;
    int wave = tid >> 6;
    int wm = wave >> 1, wn = wave & 1;
    int quad = lane >> 4, cl = lane & 15;
    int row0 = blockIdx.x * 128;
    int b  = row0 / Lout;
    int l0 = row0 % Lout;
    int d0 = l0 / 16;
    const bf16* Xb = X + (size_t)b*Tin*128;

    f32x4 acc[4][4] = {};

    for (int k0 = 0; k0 < 640; k0 += 64) {
        int tap = k0 / 128;
        int icb = k0 % 128;
        #pragma unroll
        for (int it = 0; it < 4; ++it) {
            int idx = it*256 + tid;
            int r = idx >> 3, kof = (idx & 7) * 8;
            int t = 2*(l0 + r) - 2 + tap;
            bf16x8 z = {0,0,0,0,0,0,0,0};
            if (t >= 0 && t < Tin) z = *(const bf16x8*)(Xb + (size_t)t*128 + icb + kof);
            *(bf16x8*)&As[r][kof] = z;
        }
        #pragma unroll
        for (int it = 0; it < 4; ++it) {
            int idx = it*256 + tid;
            int n = idx >> 3, kof = (idx & 7) * 8;
            *(bf16x8*)&Bs[n][kof] = *(const bf16x8*)(wB + (size_t)n*640 + k0 + kof);
        }
        __syncthreads();
        #pragma unroll
        for (int kk = 0; kk < 64; kk += 32) {
            bf16x8 af[4], bfr[4];
            #pragma unroll
            for (int i = 0; i < 4; ++i)
                af[i] = *(const bf16x8*)&As[wm*64 + i*16 + cl][kk + quad*8];
            #pragma unroll
            for (int j = 0; j < 4; ++j)
                bfr[j] = *(const bf16x8*)&Bs[wn*64 + j*16 + cl][kk + quad*8];
            #pragma unroll
            for (int i = 0; i < 4; ++i)
                #pragma unroll
                for (int j = 0; j < 4; ++j)
                    acc[i][j] = __builtin_amdgcn_mfma_f32_16x16x32_bf16(
                                    af[i], bfr[j], acc[i][j], 0, 0, 0);
        }
        __syncthreads();
    }

    #pragma unroll
    for (int j = 0; j < 4; ++j) {
        int gcol = wn*64 + j*16 + cl;
        float bv = bias[gcol];
        #pragma unroll
        for (int i = 0; i < 4; ++i) {
            float sp = 0.f;
            #pragma unroll
            for (int r = 0; r < 4; ++r) sp += fmaxf(acc[i][j][r] + bv, 0.f);
            sp += __shfl_xor(sp, 16);
            sp += __shfl_xor(sp, 32);
            if (quad == 0) {
                int d = d0 + wm*4 + i;
                outp[(size_t)b*8192 + gcol*64 + d] = sp * (1.f/16.f);
            }
        }
    }
}

extern "C" void kernel_launch(void* const* d_in, const int* in_sizes, int n_in,
                              void* d_out, int out_size, void* d_ws, size_t ws_size,
                              hipStream_t stream)
{
    (void)in_sizes; (void)n_in; (void)out_size; (void)ws_size;
    const float* x_in    = (const float*)d_in[0];
    const float* ln1_g   = (const float*)d_in[1];
    const float* ln1_b   = (const float*)d_in[2];
    const float* ln2_g   = (const float*)d_in[3];
    const float* ln2_b   = (const float*)d_in[4];
    const float* Lam_re  = (const float*)d_in[5];
    const float* Lam_im  = (const float*)d_in[6];
    const float* B_re    = (const float*)d_in[7];
    const float* B_im    = (const float*)d_in[8];
    const float* C_re    = (const float*)d_in[9];
    const float* C_im    = (const float*)d_in[10];
    const float* D_skip  = (const float*)d_in[11];
    const float* log_step= (const float*)d_in[12];
    const float* W1      = (const float*)d_in[13];
    const float* b1      = (const float*)d_in[14];
    const float* W2      = (const float*)d_in[15];
    const float* b2      = (const float*)d_in[16];
    const float* conv1_w = (const float*)d_in[17];
    const float* conv1_b = (const float*)d_in[18];
    const float* conv2_w = (const float*)d_in[19];
    const float* conv2_b = (const float*)d_in[20];
    float* out = (float*)d_out;

    // Workspace (~188 MB): X fp32 64MB | Cbuf bf16 [BT,256] 64MB | Abf(ud) bf16 32MB
    //                      | conv1out bf16 16MB | params+carry ~3MB
    char* ws = (char*)d_ws;
    float* X      = (float*)(ws);
    bf16*  Cbuf   = (bf16*) (ws + (size_t)67108864);
    bf16*  Abf    = (bf16*) (ws + (size_t)134217728);
    bf16*  Cv1    = (bf16*) (ws + (size_t)167772160);
    char*  wreg   = ws + (size_t)184549376;
    bf16*   Wbu_bf = (bf16*)(wreg);                  // 131072
    bf16*   Wc_bf  = (bf16*)(wreg + 131072);         // 131072
    bf16*   W1_bf  = (bf16*)(wreg + 262144);         // 131072
    bf16*   W2_bf  = (bf16*)(wreg + 393216);         // 131072
    float*  Sb     = (float*)(wreg + 524288);        // 2048
    float*  biasb  = (float*)(wreg + 526336);        // 2048
    float*  S1     = (float*)(wreg + 528384);        // 2048
    float*  bias1p = (float*)(wreg + 530432);        // 2048
    float*  gd     = (float*)(wreg + 532480);        // 1024
    float*  bd     = (float*)(wreg + 533504);        // 1024
    float4* coefs  = (float4*)(wreg + 534528);       // 4096
    bf16*   wB1    = (bf16*)(wreg + 538624);         // 163840
    bf16*   wB2    = (bf16*)(wreg + 702464);         // 163840
    float2* carry  = (float2*)(wreg + 866304);       // 2 MB

    prep_s5<<<2, 128, 0, stream>>>(Lam_re, Lam_im, B_re, B_im, C_re, C_im, log_step,
                                   ln1_g, ln1_b, D_skip,
                                   Wbu_bf, Wc_bf, Sb, biasb, gd, bd, coefs);
    prep_w1<<<2, 256, 0, stream>>>(W1, b1, ln2_g, ln2_b, W1_bf, S1, bias1p);
    prep_w2<<<2, 128, 0, stream>>>(W2, W2_bf);
    prep_wB<<<640, 256, 0, stream>>>(conv1_w, conv2_w, wB1, wB2);

    for (int i = 0; i < 2; ++i) {
        const float* src = (i == 0) ? x_in : X;     // layer input / residual
        // ---- S5 sub-block: fused LN+Wbu (writes Bu + ud), scan, Wc+resid+ud ----
        lngemm<1><<<512, 1024, 0, stream>>>(
            src, Wbu_bf + (size_t)i*32768, Sb + i*256, biasb + i*256,
            Cbuf, gd + i*128, bd + i*128, Abf);
        scan_local<<<1024, 256, 0, stream>>>((unsigned int*)Cbuf, coefs + i*NST, carry);
        scan_carry<<<16, 256, 0, stream>>>(carry, coefs + i*NST);
        scan_fix<<<1024, 256, 0, stream>>>((unsigned int*)Cbuf, coefs + i*NST, carry);
        gemm2<3><<<512, 1024, 0, stream>>>(
            Cbuf, Wc_bf + (size_t)i*32768, X, nullptr, src, Abf);
        // ---- MLP sub-block: fused LN+W1+gelu, W2+bias+resid ----
        lngemm<0><<<512, 1024, 0, stream>>>(
            X, W1_bf + (size_t)i*32768, S1 + i*256, bias1p + i*256,
            Cbuf, nullptr, nullptr, nullptr);
        gemm2<2><<<512, 1024, 0, stream>>>(
            Cbuf, W2_bf + (size_t)i*32768, X, b2 + i*HD, X, nullptr);
    }

    // ---- head: conv1 (X -> bf16) -> conv2+pool (-> d_out) ----
    conv1_mfma<<<512, 256, 0, stream>>>(X, wB1, conv1_b, Cv1, 4096, 2048);
    conv2_pool<<<256, 256, 0, stream>>>(Cv1, wB2, conv2_b, out, 2048, 1024);
}

// Round 8
// 678.225 us; speedup vs baseline: 1.5223x; 1.0246x over previous
//
#include <hip/hip_runtime.h>
#include <math.h>

#define BATCH 32
#define TSEQ  4096
#define HD    128
#define NST   128
#define BT    (BATCH*TSEQ)     // 131072
#define LC    64               // scan chunk length
#define NCHK  (TSEQ/LC)        // 64 chunks

typedef unsigned short bf16;
typedef __attribute__((ext_vector_type(8))) short bf16x8;   // 8 bf16 = 4 VGPRs (MFMA A/B frag)
typedef __attribute__((ext_vector_type(4))) float f32x4;    // MFMA C/D frag

__device__ inline float bf2f(bf16 s) {
    union { unsigned int u; float f; } v; v.u = ((unsigned int)s) << 16; return v.f;
}
__device__ inline bf16 f2bf(float f) {
    union { float f; unsigned int u; } v; v.f = f;
    unsigned int u = v.u;
    unsigned int r = (u + 0x7fffu + ((u >> 16) & 1u)) >> 16;
    return (bf16)r;
}
// pack two f32 -> bf16 pair (round-half-up) in ~3 VALU via v_perm
__device__ inline unsigned int pkpair(float lo, float hi) {
    union { float f; unsigned int u; } a, b;
    a.f = lo; b.f = hi;
    return __builtin_amdgcn_perm(b.u + 0x8000u, a.u + 0x8000u, 0x07060302u);
}
__device__ inline bf16x8 pack8(const float* f) {
    union { bf16x8 v; unsigned int u[4]; } t;
    t.u[0] = pkpair(f[0], f[1]);
    t.u[1] = pkpair(f[2], f[3]);
    t.u[2] = pkpair(f[4], f[5]);
    t.u[3] = pkpair(f[6], f[7]);
    return t.v;
}
__device__ inline float2 cmul2(float2 a, float2 b) {
    return make_float2(a.x*b.x - a.y*b.y, a.x*b.y + a.y*b.x);
}
// tanh-form gelu: max |diff vs exact erf-gelu| ~1e-3, under bf16 noise here
__device__ inline float gelu_f(float x) {
    float u = x*(0.7978845608f + 0.0356774081f*x*x);
    return __fdividef(x, 1.f + __expf(-2.f*u));
}
__device__ inline float2 upk(unsigned int w) {     // bf16 pair -> fp32 pair
    union { unsigned int u; float f; } a, b;
    a.u = w << 16; b.u = w & 0xffff0000u;
    return make_float2(a.f, b.f);
}
__device__ inline unsigned int pk(float2 x) { return pkpair(x.x, x.y); }

// ---------------- S5 param prep: g-folded W'bu, S/bias corrections, Wc, gd/bd, coefs ----
__global__ void prep_s5(const float* __restrict__ Lam_re, const float* __restrict__ Lam_im,
                        const float* __restrict__ B_re,  const float* __restrict__ B_im,
                        const float* __restrict__ C_re,  const float* __restrict__ C_im,
                        const float* __restrict__ log_step,
                        const float* __restrict__ ln1_g, const float* __restrict__ ln1_b,
                        const float* __restrict__ D_skip,
                        bf16* __restrict__ Wbu_bf,  // [2][256][128], row 2n=Re 2n+1=Im, g-folded
                        bf16* __restrict__ Wc_bf,   // [2][128][256], col 2n=2Cre 2n+1=-2Cim
                        float* __restrict__ Sb, float* __restrict__ biasb,   // [2][256]
                        float* __restrict__ gd, float* __restrict__ bd,      // [2][128]
                        float4* __restrict__ coefs)
{
    int i = blockIdx.x, n = threadIdx.x;
    int in = i*NST + n;
    float lr = Lam_re[in], li = Lam_im[in];
    float dt = expf(log_step[in]);
    float ea = expf(lr*dt);
    float ar = ea*cosf(li*dt), ai = ea*sinf(li*dt);
    float xx = ar - 1.f, yy = ai;
    float den = lr*lr + li*li;
    float sr = (xx*lr + yy*li)/den;
    float si = (yy*lr - xx*li)/den;
    float2 p = make_float2(ar, ai);
    #pragma unroll
    for (int q = 0; q < 6; ++q) p = cmul2(p, p);   // a^64
    coefs[in] = make_float4(ar, ai, p.x, p.y);

    const float* g  = ln1_g + i*HD;
    const float* bb = ln1_b + i*HD;
    const float* br = B_re + (size_t)in*HD;
    const float* bi = B_im + (size_t)in*HD;
    bf16* wb = Wbu_bf + (size_t)i*256*128;
    float s_re = 0.f, s_im = 0.f, bc_re = 0.f, bc_im = 0.f;
    for (int h = 0; h < HD; ++h) {
        float wre = sr*br[h] - si*bi[h];
        float wim = sr*bi[h] + si*br[h];
        bf16 wrb = f2bf(g[h]*wre), wib = f2bf(g[h]*wim);
        wb[(2*n)*128 + h]   = wrb;
        wb[(2*n+1)*128 + h] = wib;
        s_re += bf2f(wrb); s_im += bf2f(wib);
        bc_re += bb[h]*wre; bc_im += bb[h]*wim;
    }
    Sb[i*256 + 2*n] = s_re;     Sb[i*256 + 2*n+1] = s_im;
    biasb[i*256 + 2*n] = bc_re; biasb[i*256 + 2*n+1] = bc_im;

    const float* cr = C_re + (size_t)i*HD*NST;
    const float* ci = C_im + (size_t)i*HD*NST;
    bf16* wc = Wc_bf + (size_t)i*128*256;
    for (int h = 0; h < HD; ++h) {
        wc[h*256 + 2*n]   = f2bf( 2.f * cr[h*NST + n]);
        wc[h*256 + 2*n+1] = f2bf(-2.f * ci[h*NST + n]);
    }
    gd[i*HD + n] = g[n]*D_skip[i*HD + n];
    bd[i*HD + n] = bb[n]*D_skip[i*HD + n];
}

// W1 -> g2-folded bf16 [f][h] + S1/bias1' (bias1' includes b1)
__global__ void prep_w1(const float* __restrict__ W1, const float* __restrict__ b1,
                        const float* __restrict__ ln2_g, const float* __restrict__ ln2_b,
                        bf16* __restrict__ W1_bf, float* __restrict__ S1,
                        float* __restrict__ bias1p)
{
    int i = blockIdx.x, f = threadIdx.x;       // f in [0,256)
    const float* g  = ln2_g + i*HD;
    const float* bb = ln2_b + i*HD;
    bf16* w = W1_bf + (size_t)i*256*128;
    float S = 0.f, bi_ = b1[i*256 + f];
    for (int h = 0; h < HD; ++h) {
        float wv = W1[(size_t)i*32768 + h*256 + f];
        bf16 wbv = f2bf(g[h]*wv);
        w[f*128 + h] = wbv;
        S += bf2f(wbv);
        bi_ += bb[h]*wv;
    }
    S1[i*256 + f] = S;
    bias1p[i*256 + f] = bi_;
}

// W2 -> plain bf16 transposed [h][f]
__global__ void prep_w2(const float* __restrict__ W2, bf16* __restrict__ W2_bf)
{
    int i = blockIdx.x, h = threadIdx.x;       // h in [0,128)
    bf16* w = W2_bf + (size_t)i*128*256;
    for (int f = 0; f < 256; ++f)
        w[h*256 + f] = f2bf(W2[(size_t)i*32768 + f*128 + h]);
}

// conv weights [c][ic][tap] -> bf16 [c][tap*128+ic]
__global__ void prep_wB(const float* __restrict__ w1, const float* __restrict__ w2,
                        bf16* __restrict__ wB1, bf16* __restrict__ wB2)
{
    int idx = blockIdx.x*256 + threadIdx.x;
    if (idx >= 163840) return;
    const float* w = (idx < 81920) ? w1 : w2;
    bf16* wb       = (idx < 81920) ? wB1 : wB2;
    int r   = idx % 81920;
    int c   = r / 640;
    int tap = (r % 640) / 128;
    int ic  = r % 128;
    wb[r] = f2bf(w[(c*128 + ic)*5 + tap]);
}

// ---------------- fused LN + GEMM (K=128, N=256), bf16 out, persistent waves ----------
// Operand-swapped MFMA: D = W x act^T -> lane cl owns output row t = s*16+cl directly
// (no LDS transpose). LN folded: out_n = rs*acc - mu*rs*S_n + bias_n  [, gelu].
// UD=1: also writes ud = xn*dskip (bf16), no activation (Bu). UD=0: gelu (h).
template<int UD>
__global__ __launch_bounds__(1024, 4) void lngemm(
    const float* __restrict__ A,       // [BT,128] fp32
    const bf16* __restrict__ Bt,       // [256][128] g-folded
    const float* __restrict__ Svec, const float* __restrict__ bvec,  // [256]
    bf16* __restrict__ outB,           // [BT,256]
    const float* __restrict__ gdp, const float* __restrict__ bdp,    // [128]
    bf16* __restrict__ udout)          // [BT,128]
{
    __shared__ bf16 Bs[256*136];       // 69632 B (+8 pad per row)
    __shared__ float Sl[256], bl[256];
    __shared__ float gdl[128], bdl[128];

    int tid = threadIdx.x;
    #pragma unroll
    for (int it = 0; it < 4; ++it) {
        int f = it*1024 + tid;
        int n = f >> 4, kk = (f & 15)*8;
        *(bf16x8*)&Bs[n*136 + kk] = *(const bf16x8*)(Bt + n*128 + kk);
    }
    if (tid < 256) { Sl[tid] = Svec[tid]; bl[tid] = bvec[tid]; }
    if constexpr (UD) {
        if (tid >= 256 && tid < 384) { gdl[tid-256] = gdp[tid-256]; bdl[tid-256] = bdp[tid-256]; }
    }
    __syncthreads();

    int wid = tid >> 6, lane = tid & 63;
    int quad = lane >> 4, cl = lane & 15;
    int s = blockIdx.x*16 + wid;                  // strip [0,8192)
    size_t row = (size_t)s*16 + cl;
    const float* ar = A + row*128;

    float v[32];
    #pragma unroll
    for (int ks = 0; ks < 4; ++ks) {
        float4 f0 = *(const float4*)(ar + quad*8 + ks*32);
        float4 f1 = *(const float4*)(ar + quad*8 + ks*32 + 4);
        v[ks*8+0]=f0.x; v[ks*8+1]=f0.y; v[ks*8+2]=f0.z; v[ks*8+3]=f0.w;
        v[ks*8+4]=f1.x; v[ks*8+5]=f1.y; v[ks*8+6]=f1.z; v[ks*8+7]=f1.w;
    }
    // full-row LN stats per lane (cross-quad reduce; identical for 4 quads of same cl)
    float sm = 0.f, sq = 0.f;
    #pragma unroll
    for (int j = 0; j < 32; ++j) { sm += v[j]; sq += v[j]*v[j]; }
    sm += __shfl_xor(sm, 16); sm += __shfl_xor(sm, 32);
    sq += __shfl_xor(sq, 16); sq += __shfl_xor(sq, 32);
    float mu = sm * (1.f/128.f);
    float rs = rsqrtf(sq*(1.f/128.f) - mu*mu + 1e-5f);
    float mr = mu*rs;

    bf16x8 af[4];
    #pragma unroll
    for (int ks = 0; ks < 4; ++ks) af[ks] = pack8(&v[ks*8]);

    if constexpr (UD) {
        #pragma unroll
        for (int ks = 0; ks < 4; ++ks) {
            float un[8];
            const float* gq = &gdl[quad*8 + ks*32];
            const float* bq = &bdl[quad*8 + ks*32];
            #pragma unroll
            for (int j = 0; j < 8; ++j) un[j] = (v[ks*8+j] - mu)*rs*gq[j] + bq[j];
            *(bf16x8*)(udout + row*128 + quad*8 + ks*32) = pack8(un);
        }
    }

    #pragma unroll
    for (int half = 0; half < 2; ++half) {
        f32x4 acc[8] = {};
        #pragma unroll
        for (int nt = 0; nt < 8; ++nt) {
            const bf16* wrp = &Bs[((half*8+nt)*16 + cl)*136 + quad*8];
            #pragma unroll
            for (int ks = 0; ks < 4; ++ks)
                acc[nt] = __builtin_amdgcn_mfma_f32_16x16x32_bf16(
                              *(const bf16x8*)(wrp + ks*32), af[ks], acc[nt], 0, 0, 0);
        }
        // D: col=cl -> t=row, rows quad*4+r -> n within 16-group. Direct store.
        #pragma unroll
        for (int nt = 0; nt < 8; ++nt) {
            int n0 = (half*8+nt)*16 + quad*4;
            float4 S4 = *(const float4*)&Sl[n0];
            float4 b4 = *(const float4*)&bl[n0];
            float4 o;
            o.x = rs*acc[nt][0] - mr*S4.x + b4.x;
            o.y = rs*acc[nt][1] - mr*S4.y + b4.y;
            o.z = rs*acc[nt][2] - mr*S4.z + b4.z;
            o.w = rs*acc[nt][3] - mr*S4.w + b4.w;
            if constexpr (!UD) {
                o.x = gelu_f(o.x); o.y = gelu_f(o.y);
                o.z = gelu_f(o.z); o.w = gelu_f(o.w);
            }
            uint2 pu = make_uint2(pkpair(o.x, o.y), pkpair(o.z, o.w));
            *(uint2*)(outB + row*256 + n0) = pu;
        }
    }
}

// ---------------- GEMM K=256 N=128 (bf16 A), fp32 out, persistent waves --------------
// Operand-swapped: lane cl owns output row t directly; no LDS transpose.
// EPI: 2 = acc+bias+resid; 3 = resid+acc+ud (ud pre-multiplied by dskip)
template<int EPI>
__global__ __launch_bounds__(1024, 4) void gemm2(
    const bf16* __restrict__ A,        // [BT,256]
    const bf16* __restrict__ Bt,       // [128][256]
    float* out,                        // [BT,128] (may alias resid, same-elem r-then-w)
    const float* __restrict__ bias,
    const float* resid,
    const bf16* __restrict__ ud)
{
    __shared__ bf16 Bs[128*264];       // 67584 B

    int tid = threadIdx.x;
    #pragma unroll
    for (int it = 0; it < 4; ++it) {
        int f = it*1024 + tid;
        int n = f >> 5, kk = (f & 31)*8;
        *(bf16x8*)&Bs[n*264 + kk] = *(const bf16x8*)(Bt + n*256 + kk);
    }
    __syncthreads();

    int wid = tid >> 6, lane = tid & 63;
    int quad = lane >> 4, cl = lane & 15;
    int s = blockIdx.x*16 + wid;
    size_t row = (size_t)s*16 + cl;

    bf16x8 af[8];
    #pragma unroll
    for (int ks = 0; ks < 8; ++ks)
        af[ks] = *(const bf16x8*)(A + row*256 + quad*8 + ks*32);

    f32x4 acc[8] = {};
    #pragma unroll
    for (int nt = 0; nt < 8; ++nt) {
        const bf16* wrp = &Bs[(nt*16 + cl)*264 + quad*8];
        #pragma unroll
        for (int ks = 0; ks < 8; ++ks)
            acc[nt] = __builtin_amdgcn_mfma_f32_16x16x32_bf16(
                          *(const bf16x8*)(wrp + ks*32), af[ks], acc[nt], 0, 0, 0);
    }

    #pragma unroll
    for (int nt = 0; nt < 8; ++nt) {
        int n0 = nt*16 + quad*4;
        size_t oidx = row*128 + n0;
        float4 rv = *(const float4*)(resid + oidx);
        float4 o;
        if (EPI == 2) {
            float4 bv = *(const float4*)(bias + n0);
            o.x = acc[nt][0] + bv.x + rv.x; o.y = acc[nt][1] + bv.y + rv.y;
            o.z = acc[nt][2] + bv.z + rv.z; o.w = acc[nt][3] + bv.w + rv.w;
        } else {
            ushort4 u4 = *(const ushort4*)(ud + oidx);
            o.x = rv.x + acc[nt][0] + bf2f(u4.x); o.y = rv.y + acc[nt][1] + bf2f(u4.y);
            o.z = rv.z + acc[nt][2] + bf2f(u4.z); o.w = rv.w + acc[nt][3] + bf2f(u4.w);
        }
        *(float4*)(out + oidx) = o;
    }
}

// ---------------- chunked scan on bf16-pair xs: x_t = a*x_{t-1} + Bu_t ---------------
__global__ __launch_bounds__(256) void scan_local(unsigned int* __restrict__ xs,
                                                  const float4* __restrict__ coefs,
                                                  float2* __restrict__ carry)
{
    int flat = blockIdx.x*256 + threadIdx.x;  // 2^18
    int n = flat & 127;
    int b = (flat >> 7) & 31;
    int c = flat >> 12;
    float4 cf = coefs[n];
    float2 a = make_float2(cf.x, cf.y);
    unsigned int* base = xs + ((size_t)(b*TSEQ + c*LC))*NST + n;
    float2 x = make_float2(0.f, 0.f);
    for (int j = 0; j < LC; ++j) {
        float2 v = upk(base[(size_t)j*NST]);
        x = make_float2(a.x*x.x - a.y*x.y + v.x, a.x*x.y + a.y*x.x + v.y);
        base[(size_t)j*NST] = pk(x);
    }
    carry[c*(BATCH*NST) + b*NST + n] = x;
}

__global__ void scan_carry(float2* __restrict__ carry, const float4* __restrict__ coefs)
{
    int flat = blockIdx.x*256 + threadIdx.x;  // 4096 = B*N
    int n = flat & 127;
    float4 cf = coefs[n];
    float2 aL = make_float2(cf.z, cf.w);
    float2 x = make_float2(0.f, 0.f);
    for (int c = 0; c < NCHK; ++c) {
        float2* p = carry + c*(BATCH*NST) + flat;
        float2 v = *p;
        *p = x;                                // exclusive prefix
        x = make_float2(aL.x*x.x - aL.y*x.y + v.x, aL.x*x.y + aL.y*x.x + v.y);
    }
}

__global__ __launch_bounds__(256) void scan_fix(unsigned int* __restrict__ xs,
                                                const float4* __restrict__ coefs,
                                                const float2* __restrict__ carry)
{
    int flat = blockIdx.x*256 + threadIdx.x;
    int n = flat & 127;
    int b = (flat >> 7) & 31;
    int c = flat >> 12;
    if (c == 0) return;
    float2 cin = carry[c*(BATCH*NST) + b*NST + n];
    float4 cf = coefs[n];
    float2 a = make_float2(cf.x, cf.y);
    unsigned int* base = xs + ((size_t)(b*TSEQ + c*LC))*NST + n;
    float2 p = a;
    for (int j = 0; j < LC; ++j) {
        float2 add = cmul2(p, cin);
        float2 v = upk(base[(size_t)j*NST]);
        base[(size_t)j*NST] = pk(make_float2(v.x + add.x, v.y + add.y));
        p = cmul2(p, a);
    }
}

// ---------------- conv1: fp32 in, implicit-im2col MFMA (operand-swapped), bf16 out ----
__global__ __launch_bounds__(256, 4) void conv1_mfma(
    const float* __restrict__ X,
    const bf16* __restrict__ wB,    // [128][640]
    const float* __restrict__ bias,
    bf16* __restrict__ out,         // [B*Lout][128]
    int Tin, int Lout)
{
    __shared__ bf16 As[128][72];
    __shared__ bf16 Bs[128][72];
    int tid  = threadIdx.x;
    int lane = tid & 63;
    int wave = tid >> 6;
    int wm = wave >> 1, wn = wave & 1;
    int quad = lane >> 4, cl = lane & 15;
    int row0 = blockIdx.x * 128;
    int b  = row0 / Lout;
    int l0 = row0 % Lout;
    const float* Xb = X + (size_t)b*Tin*128;

    f32x4 acc[4][4] = {};

    for (int k0 = 0; k0 < 640; k0 += 64) {
        int tap = k0 / 128;
        int icb = k0 % 128;
        #pragma unroll
        for (int it = 0; it < 8; ++it) {
            int idx = it*256 + tid;
            int r = idx >> 4, kof = (idx & 15) * 4;
            int t = 2*(l0 + r) - 2 + tap;
            uint2 h = make_uint2(0u, 0u);
            if (t >= 0 && t < Tin) {
                float4 f = *(const float4*)(Xb + (size_t)t*128 + icb + kof);
                h = make_uint2(pkpair(f.x, f.y), pkpair(f.z, f.w));
            }
            *(uint2*)&As[r][kof] = h;
        }
        #pragma unroll
        for (int it = 0; it < 4; ++it) {
            int idx = it*256 + tid;
            int n = idx >> 3, kof = (idx & 7) * 8;
            *(bf16x8*)&Bs[n][kof] = *(const bf16x8*)(wB + (size_t)n*640 + k0 + kof);
        }
        __syncthreads();
        #pragma unroll
        for (int kk = 0; kk < 64; kk += 32) {
            bf16x8 af[4], bfr[4];
            #pragma unroll
            for (int i = 0; i < 4; ++i)
                af[i] = *(const bf16x8*)&As[wm*64 + i*16 + cl][kk + quad*8];
            #pragma unroll
            for (int j = 0; j < 4; ++j)
                bfr[j] = *(const bf16x8*)&Bs[wn*64 + j*16 + cl][kk + quad*8];
            #pragma unroll
            for (int i = 0; i < 4; ++i)
                #pragma unroll
                for (int j = 0; j < 4; ++j)
                    acc[i][j] = __builtin_amdgcn_mfma_f32_16x16x32_bf16(
                                    bfr[j], af[i], acc[i][j], 0, 0, 0);
        }
        __syncthreads();
    }

    // D: col=cl -> output position l, rows quad*4+r -> channel. Direct uint2 stores.
    #pragma unroll
    for (int i = 0; i < 4; ++i) {
        int grow = row0 + wm*64 + i*16 + cl;
        #pragma unroll
        for (int j = 0; j < 4; ++j) {
            int gcol = wn*64 + j*16 + quad*4;
            float4 bv = *(const float4*)(bias + gcol);
            float4 t;
            t.x = fmaxf(acc[i][j][0] + bv.x, 0.f); t.y = fmaxf(acc[i][j][1] + bv.y, 0.f);
            t.z = fmaxf(acc[i][j][2] + bv.z, 0.f); t.w = fmaxf(acc[i][j][3] + bv.w, 0.f);
            uint2 pu = make_uint2(pkpair(t.x, t.y), pkpair(t.z, t.w));
            *(uint2*)(out + (size_t)grow*128 + gcol) = pu;
        }
    }
}

// ---------------- conv2 (bf16 in) + fused relu + avg pool (operand-swapped) ----------
// After swap: lane cl = position l within 16-window -> pool = shuffle-reduce over cl.
__global__ __launch_bounds__(256, 4) void conv2_pool(
    const bf16* __restrict__ X,     // [B][Tin][128]
    const bf16* __restrict__ wB,    // [128][640]
    const float* __restrict__ bias,
    float* __restrict__ outp,       // [B][128][64]
    int Tin, int Lout)
{
    __shared__ bf16 As[128][72];
    __shared__ bf16 Bs[128][72];
    int tid  = threadIdx.x;
    int lane = tid & 63;
    int wave = tid >> 6;
    int wm = wave >> 1, wn = wave & 1;
    int quad = lane >> 4, cl = lane & 15;
    int row0 = blockIdx.x * 128;
    int b  = row0 / Lout;
    int l0 = row0 % Lout;
    int d0 = l0 / 16;
    const bf16* Xb = X + (size_t)b*Tin*128;

    f32x4 acc[4][4] = {};

    for (int k0 = 0; k0 < 640; k0 += 64) {
        int tap = k0 / 128;
        int icb = k0 % 128;
        #pragma unroll
        for (int it = 0; it < 4; ++it) {
            int idx = it*256 + tid;
            int r = idx >> 3, kof = (idx & 7) * 8;
            int t = 2*(l0 + r) - 2 + tap;
            bf16x8 z = {0,0,0,0,0,0,0,0};
            if (t >= 0 && t < Tin) z = *(const bf16x8*)(Xb + (size_t)t*128 + icb + kof);
            *(bf16x8*)&As[r][kof] = z;
        }
        #pragma unroll
        for (int it = 0; it < 4; ++it) {
            int idx = it*256 + tid;
            int n = idx >> 3, kof = (idx & 7) * 8;
            *(bf16x8*)&Bs[n][kof] = *(const bf16x8*)(wB + (size_t)n*640 + k0 + kof);
        }
        __syncthreads();
        #pragma unroll
        for (int kk = 0; kk < 64; kk += 32) {
            bf16x8 af[4], bfr[4];
            #pragma unroll
            for (int i = 0; i < 4; ++i)
                af[i] = *(const bf16x8*)&As[wm*64 + i*16 + cl][kk + quad*8];
            #pragma unroll
            for (int j = 0; j < 4; ++j)
                bfr[j] = *(const bf16x8*)&Bs[wn*64 + j*16 + cl][kk + quad*8];
            #pragma unroll
            for (int i = 0; i < 4; ++i)
                #pragma unroll
                for (int j = 0; j < 4; ++j)
                    acc[i][j] = __builtin_amdgcn_mfma_f32_16x16x32_bf16(
                                    bfr[j], af[i], acc[i][j], 0, 0, 0);
        }
        __syncthreads();
    }

    // lane (quad,cl): channels gcol..+3 (rows), position l = group + cl (col).
    #pragma unroll
    for (int j = 0; j < 4; ++j) {
        int gcol = wn*64 + j*16 + quad*4;
        float4 bv = *(const float4*)(bias + gcol);
        #pragma unroll
        for (int i = 0; i < 4; ++i) {
            float4 sp;
            sp.x = fmaxf(acc[i][j][0] + bv.x, 0.f);
            sp.y = fmaxf(acc[i][j][1] + bv.y, 0.f);
            sp.z = fmaxf(acc[i][j][2] + bv.z, 0.f);
            sp.w = fmaxf(acc[i][j][3] + bv.w, 0.f);
            #pragma unroll
            for (int off = 1; off <= 8; off <<= 1) {
                sp.x += __shfl_xor(sp.x, off);
                sp.y += __shfl_xor(sp.y, off);
                sp.z += __shfl_xor(sp.z, off);
                sp.w += __shfl_xor(sp.w, off);
            }
            if (cl == 0) {
                int d = d0 + wm*4 + i;
                float* op = outp + (size_t)b*8192 + (size_t)gcol*64 + d;
                op[0]   = sp.x * (1.f/16.f);
                op[64]  = sp.y * (1.f/16.f);
                op[128] = sp.z * (1.f/16.f);
                op[192] = sp.w * (1.f/16.f);
            }
        }
    }
}

extern "C" void kernel_launch(void* const* d_in, const int* in_sizes, int n_in,
                              void* d_out, int out_size, void* d_ws, size_t ws_size,
                              hipStream_t stream)
{
    (void)in_sizes; (void)n_in; (void)out_size; (void)ws_size;
    const float* x_in    = (const float*)d_in[0];
    const float* ln1_g   = (const float*)d_in[1];
    const float* ln1_b   = (const float*)d_in[2];
    const float* ln2_g   = (const float*)d_in[3];
    const float* ln2_b   = (const float*)d_in[4];
    const float* Lam_re  = (const float*)d_in[5];
    const float* Lam_im  = (const float*)d_in[6];
    const float* B_re    = (const float*)d_in[7];
    const float* B_im    = (const float*)d_in[8];
    const float* C_re    = (const float*)d_in[9];
    const float* C_im    = (const float*)d_in[10];
    const float* D_skip  = (const float*)d_in[11];
    const float* log_step= (const float*)d_in[12];
    const float* W1      = (const float*)d_in[13];
    const float* b1      = (const float*)d_in[14];
    const float* W2      = (const float*)d_in[15];
    const float* b2      = (const float*)d_in[16];
    const float* conv1_w = (const float*)d_in[17];
    const float* conv1_b = (const float*)d_in[18];
    const float* conv2_w = (const float*)d_in[19];
    const float* conv2_b = (const float*)d_in[20];
    float* out = (float*)d_out;

    // Workspace (~188 MB): X fp32 64MB | Cbuf bf16 [BT,256] 64MB | Abf(ud) bf16 32MB
    //                      | conv1out bf16 16MB | params+carry ~3MB
    char* ws = (char*)d_ws;
    float* X      = (float*)(ws);
    bf16*  Cbuf   = (bf16*) (ws + (size_t)67108864);
    bf16*  Abf    = (bf16*) (ws + (size_t)134217728);
    bf16*  Cv1    = (bf16*) (ws + (size_t)167772160);
    char*  wreg   = ws + (size_t)184549376;
    bf16*   Wbu_bf = (bf16*)(wreg);                  // 131072
    bf16*   Wc_bf  = (bf16*)(wreg + 131072);         // 131072
    bf16*   W1_bf  = (bf16*)(wreg + 262144);         // 131072
    bf16*   W2_bf  = (bf16*)(wreg + 393216);         // 131072
    float*  Sb     = (float*)(wreg + 524288);        // 2048
    float*  biasb  = (float*)(wreg + 526336);        // 2048
    float*  S1     = (float*)(wreg + 528384);        // 2048
    float*  bias1p = (float*)(wreg + 530432);        // 2048
    float*  gd     = (float*)(wreg + 532480);        // 1024
    float*  bd     = (float*)(wreg + 533504);        // 1024
    float4* coefs  = (float4*)(wreg + 534528);       // 4096
    bf16*   wB1    = (bf16*)(wreg + 538624);         // 163840
    bf16*   wB2    = (bf16*)(wreg + 702464);         // 163840
    float2* carry  = (float2*)(wreg + 866304);       // 2 MB

    prep_s5<<<2, 128, 0, stream>>>(Lam_re, Lam_im, B_re, B_im, C_re, C_im, log_step,
                                   ln1_g, ln1_b, D_skip,
                                   Wbu_bf, Wc_bf, Sb, biasb, gd, bd, coefs);
    prep_w1<<<2, 256, 0, stream>>>(W1, b1, ln2_g, ln2_b, W1_bf, S1, bias1p);
    prep_w2<<<2, 128, 0, stream>>>(W2, W2_bf);
    prep_wB<<<640, 256, 0, stream>>>(conv1_w, conv2_w, wB1, wB2);

    for (int i = 0; i < 2; ++i) {
        const float* src = (i == 0) ? x_in : X;     // layer input / residual
        // ---- S5 sub-block: fused LN+Wbu (writes Bu + ud), scan, Wc+resid+ud ----
        lngemm<1><<<512, 1024, 0, stream>>>(
            src, Wbu_bf + (size_t)i*32768, Sb + i*256, biasb + i*256,
            Cbuf, gd + i*128, bd + i*128, Abf);
        scan_local<<<1024, 256, 0, stream>>>((unsigned int*)Cbuf, coefs + i*NST, carry);
        scan_carry<<<16, 256, 0, stream>>>(carry, coefs + i*NST);
        scan_fix<<<1024, 256, 0, stream>>>((unsigned int*)Cbuf, coefs + i*NST, carry);
        gemm2<3><<<512, 1024, 0, stream>>>(
            Cbuf, Wc_bf + (size_t)i*32768, X, nullptr, src, Abf);
        // ---- MLP sub-block: fused LN+W1+gelu, W2+bias+resid ----
        lngemm<0><<<512, 1024, 0, stream>>>(
            X, W1_bf + (size_t)i*32768, S1 + i*256, bias1p + i*256,
            Cbuf, nullptr, nullptr, nullptr);
        gemm2<2><<<512, 1024, 0, stream>>>(
            Cbuf, W2_bf + (size_t)i*32768, X, b2 + i*HD, X, nullptr);
    }

    // ---- head: conv1 (X -> bf16) -> conv2+pool (-> d_out) ----
    conv1_mfma<<<512, 256, 0, stream>>>(X, wB1, conv1_b, Cv1, 4096, 2048);
    conv2_pool<<<256, 256, 0, stream>>>(Cv1, wB2, conv2_b, out, 2048, 1024);
}

// Round 9
// 675.518 us; speedup vs baseline: 1.5284x; 1.0040x over previous
//
#include <hip/hip_runtime.h>
#include <math.h>

#define BATCH 32
#define TSEQ  4096
#define HD    128
#define NST   128
#define BT    (BATCH*TSEQ)     // 131072
#define LC    64               // scan chunk length
#define NCHK  (TSEQ/LC)        // 64 chunks

typedef unsigned short bf16;
typedef __attribute__((ext_vector_type(8))) short bf16x8;   // 8 bf16 = 4 VGPRs (MFMA A/B frag)
typedef __attribute__((ext_vector_type(4))) float f32x4;    // MFMA C/D frag

__device__ inline float bf2f(bf16 s) {
    union { unsigned int u; float f; } v; v.u = ((unsigned int)s) << 16; return v.f;
}
__device__ inline bf16 f2bf(float f) {
    union { float f; unsigned int u; } v; v.f = f;
    unsigned int u = v.u;
    unsigned int r = (u + 0x7fffu + ((u >> 16) & 1u)) >> 16;
    return (bf16)r;
}
// pack two f32 -> bf16 pair (round-half-up) in ~3 VALU via v_perm
__device__ inline unsigned int pkpair(float lo, float hi) {
    union { float f; unsigned int u; } a, b;
    a.f = lo; b.f = hi;
    return __builtin_amdgcn_perm(b.u + 0x8000u, a.u + 0x8000u, 0x07060302u);
}
__device__ inline bf16x8 pack8f(float4 f0, float4 f1) {
    union { bf16x8 v; unsigned int u[4]; } t;
    t.u[0] = pkpair(f0.x, f0.y);
    t.u[1] = pkpair(f0.z, f0.w);
    t.u[2] = pkpair(f1.x, f1.y);
    t.u[3] = pkpair(f1.z, f1.w);
    return t.v;
}
__device__ inline bf16x8 pack8(const float* f) {
    union { bf16x8 v; unsigned int u[4]; } t;
    t.u[0] = pkpair(f[0], f[1]);
    t.u[1] = pkpair(f[2], f[3]);
    t.u[2] = pkpair(f[4], f[5]);
    t.u[3] = pkpair(f[6], f[7]);
    return t.v;
}
__device__ inline float2 cmul2(float2 a, float2 b) {
    return make_float2(a.x*b.x - a.y*b.y, a.x*b.y + a.y*b.x);
}
// tanh-form gelu: max |diff vs exact erf-gelu| ~1e-3, under bf16 noise here
__device__ inline float gelu_f(float x) {
    float u = x*(0.7978845608f + 0.0356774081f*x*x);
    return __fdividef(x, 1.f + __expf(-2.f*u));
}
__device__ inline float2 upk(unsigned int w) {     // bf16 pair -> fp32 pair
    union { unsigned int u; float f; } a, b;
    a.u = w << 16; b.u = w & 0xffff0000u;
    return make_float2(a.f, b.f);
}
__device__ inline unsigned int pk(float2 x) { return pkpair(x.x, x.y); }

// ---------------- S5 param prep: g-folded W'bu, S/bias corrections, Wc, gd/bd, coefs ----
__global__ void prep_s5(const float* __restrict__ Lam_re, const float* __restrict__ Lam_im,
                        const float* __restrict__ B_re,  const float* __restrict__ B_im,
                        const float* __restrict__ C_re,  const float* __restrict__ C_im,
                        const float* __restrict__ log_step,
                        const float* __restrict__ ln1_g, const float* __restrict__ ln1_b,
                        const float* __restrict__ D_skip,
                        bf16* __restrict__ Wbu_bf,  // [2][256][128], row 2n=Re 2n+1=Im, g-folded
                        bf16* __restrict__ Wc_bf,   // [2][128][256], col 2n=2Cre 2n+1=-2Cim
                        float* __restrict__ Sb, float* __restrict__ biasb,   // [2][256]
                        float* __restrict__ gd, float* __restrict__ bd,      // [2][128]
                        float4* __restrict__ coefs)
{
    int i = blockIdx.x, n = threadIdx.x;
    int in = i*NST + n;
    float lr = Lam_re[in], li = Lam_im[in];
    float dt = expf(log_step[in]);
    float ea = expf(lr*dt);
    float ar = ea*cosf(li*dt), ai = ea*sinf(li*dt);
    float xx = ar - 1.f, yy = ai;
    float den = lr*lr + li*li;
    float sr = (xx*lr + yy*li)/den;
    float si = (yy*lr - xx*li)/den;
    float2 p = make_float2(ar, ai);
    #pragma unroll
    for (int q = 0; q < 6; ++q) p = cmul2(p, p);   // a^64
    coefs[in] = make_float4(ar, ai, p.x, p.y);

    const float* g  = ln1_g + i*HD;
    const float* bb = ln1_b + i*HD;
    const float* br = B_re + (size_t)in*HD;
    const float* bi = B_im + (size_t)in*HD;
    bf16* wb = Wbu_bf + (size_t)i*256*128;
    float s_re = 0.f, s_im = 0.f, bc_re = 0.f, bc_im = 0.f;
    for (int h = 0; h < HD; ++h) {
        float wre = sr*br[h] - si*bi[h];
        float wim = sr*bi[h] + si*br[h];
        bf16 wrb = f2bf(g[h]*wre), wib = f2bf(g[h]*wim);
        wb[(2*n)*128 + h]   = wrb;
        wb[(2*n+1)*128 + h] = wib;
        s_re += bf2f(wrb); s_im += bf2f(wib);
        bc_re += bb[h]*wre; bc_im += bb[h]*wim;
    }
    Sb[i*256 + 2*n] = s_re;     Sb[i*256 + 2*n+1] = s_im;
    biasb[i*256 + 2*n] = bc_re; biasb[i*256 + 2*n+1] = bc_im;

    const float* cr = C_re + (size_t)i*HD*NST;
    const float* ci = C_im + (size_t)i*HD*NST;
    bf16* wc = Wc_bf + (size_t)i*128*256;
    for (int h = 0; h < HD; ++h) {
        wc[h*256 + 2*n]   = f2bf( 2.f * cr[h*NST + n]);
        wc[h*256 + 2*n+1] = f2bf(-2.f * ci[h*NST + n]);
    }
    gd[i*HD + n] = g[n]*D_skip[i*HD + n];
    bd[i*HD + n] = bb[n]*D_skip[i*HD + n];
}

// W1 -> g2-folded bf16 [f][h] + S1/bias1' (bias1' includes b1)
__global__ void prep_w1(const float* __restrict__ W1, const float* __restrict__ b1,
                        const float* __restrict__ ln2_g, const float* __restrict__ ln2_b,
                        bf16* __restrict__ W1_bf, float* __restrict__ S1,
                        float* __restrict__ bias1p)
{
    int i = blockIdx.x, f = threadIdx.x;       // f in [0,256)
    const float* g  = ln2_g + i*HD;
    const float* bb = ln2_b + i*HD;
    bf16* w = W1_bf + (size_t)i*256*128;
    float S = 0.f, bi_ = b1[i*256 + f];
    for (int h = 0; h < HD; ++h) {
        float wv = W1[(size_t)i*32768 + h*256 + f];
        bf16 wbv = f2bf(g[h]*wv);
        w[f*128 + h] = wbv;
        S += bf2f(wbv);
        bi_ += bb[h]*wv;
    }
    S1[i*256 + f] = S;
    bias1p[i*256 + f] = bi_;
}

// W2 -> plain bf16 transposed [h][f]
__global__ void prep_w2(const float* __restrict__ W2, bf16* __restrict__ W2_bf)
{
    int i = blockIdx.x, h = threadIdx.x;       // h in [0,128)
    bf16* w = W2_bf + (size_t)i*128*256;
    for (int f = 0; f < 256; ++f)
        w[h*256 + f] = f2bf(W2[(size_t)i*32768 + f*128 + h]);
}

// conv weights [c][ic][tap] -> bf16 [c][tap*128+ic]
__global__ void prep_wB(const float* __restrict__ w1, const float* __restrict__ w2,
                        bf16* __restrict__ wB1, bf16* __restrict__ wB2)
{
    int idx = blockIdx.x*256 + threadIdx.x;
    if (idx >= 163840) return;
    const float* w = (idx < 81920) ? w1 : w2;
    bf16* wb       = (idx < 81920) ? wB1 : wB2;
    int r   = idx % 81920;
    int c   = r / 640;
    int tap = (r % 640) / 128;
    int ic  = r % 128;
    wb[r] = f2bf(w[(c*128 + ic)*5 + tap]);
}

// ---------------- fused LN + GEMM (K=128, N=256), bf16 out, persistent waves ----------
// Operand-swapped MFMA: D = W x act^T -> lane cl owns output row t = s*16+cl directly.
// Register-diet: no fp32 row kept live; LN stats computed streaming; ud derived from af.
// UD=1: also writes ud = xn*dskip (bf16), no activation (Bu). UD=0: gelu (h).
template<int UD>
__global__ __launch_bounds__(1024, 4) void lngemm(
    const float* __restrict__ A,       // [BT,128] fp32
    const bf16* __restrict__ Bt,       // [256][128] g-folded
    const float* __restrict__ Svec, const float* __restrict__ bvec,  // [256]
    bf16* __restrict__ outB,           // [BT,256]
    const float* __restrict__ gdp, const float* __restrict__ bdp,    // [128]
    bf16* __restrict__ udout)          // [BT,128]
{
    __shared__ bf16 Bs[256*136];       // 69632 B (+8 pad per row)
    __shared__ float Sl[256], bl[256];
    __shared__ float gdl[128], bdl[128];

    int tid = threadIdx.x;
    #pragma unroll
    for (int it = 0; it < 4; ++it) {
        int f = it*1024 + tid;
        int n = f >> 4, kk = (f & 15)*8;
        *(bf16x8*)&Bs[n*136 + kk] = *(const bf16x8*)(Bt + n*128 + kk);
    }
    if (tid < 256) { Sl[tid] = Svec[tid]; bl[tid] = bvec[tid]; }
    if constexpr (UD) {
        if (tid >= 256 && tid < 384) { gdl[tid-256] = gdp[tid-256]; bdl[tid-256] = bdp[tid-256]; }
    }
    __syncthreads();

    int wid = tid >> 6, lane = tid & 63;
    int quad = lane >> 4, cl = lane & 15;
    int s = blockIdx.x*16 + wid;                  // strip [0,8192)
    size_t row = (size_t)s*16 + cl;
    const float* ar = A + row*128;

    // streaming load: stats + immediate bf16 pack (no fp32 row kept live)
    bf16x8 af[4];
    float sm = 0.f, sq = 0.f;
    #pragma unroll
    for (int ks = 0; ks < 4; ++ks) {
        float4 f0 = *(const float4*)(ar + quad*8 + ks*32);
        float4 f1 = *(const float4*)(ar + quad*8 + ks*32 + 4);
        sm += f0.x + f0.y + f0.z + f0.w + f1.x + f1.y + f1.z + f1.w;
        sq += f0.x*f0.x + f0.y*f0.y + f0.z*f0.z + f0.w*f0.w
            + f1.x*f1.x + f1.y*f1.y + f1.z*f1.z + f1.w*f1.w;
        af[ks] = pack8f(f0, f1);
    }
    // full-row stats via cross-quad reduce (4 quads of same cl share a row)
    sm += __shfl_xor(sm, 16); sm += __shfl_xor(sm, 32);
    sq += __shfl_xor(sq, 16); sq += __shfl_xor(sq, 32);
    float mu = sm * (1.f/128.f);
    float rs = rsqrtf(sq*(1.f/128.f) - mu*mu + 1e-5f);
    float mr = mu*rs;

    if constexpr (UD) {
        #pragma unroll
        for (int ks = 0; ks < 4; ++ks) {
            union { bf16x8 v; unsigned int u[4]; } aa; aa.v = af[ks];
            float un[8];
            const float* gq = &gdl[quad*8 + ks*32];
            const float* bq = &bdl[quad*8 + ks*32];
            #pragma unroll
            for (int jp = 0; jp < 4; ++jp) {
                float2 vv = upk(aa.u[jp]);
                un[2*jp+0] = (vv.x - mu)*rs*gq[2*jp+0] + bq[2*jp+0];
                un[2*jp+1] = (vv.y - mu)*rs*gq[2*jp+1] + bq[2*jp+1];
            }
            *(bf16x8*)(udout + row*128 + quad*8 + ks*32) = pack8(un);
        }
    }

    #pragma unroll
    for (int half = 0; half < 2; ++half) {
        f32x4 acc[8] = {};
        #pragma unroll
        for (int nt = 0; nt < 8; ++nt) {
            const bf16* wrp = &Bs[((half*8+nt)*16 + cl)*136 + quad*8];
            #pragma unroll
            for (int ks = 0; ks < 4; ++ks)
                acc[nt] = __builtin_amdgcn_mfma_f32_16x16x32_bf16(
                              *(const bf16x8*)(wrp + ks*32), af[ks], acc[nt], 0, 0, 0);
        }
        // D: col=cl -> t=row, rows quad*4+r -> n within 16-group. Direct store.
        #pragma unroll
        for (int nt = 0; nt < 8; ++nt) {
            int n0 = (half*8+nt)*16 + quad*4;
            float4 S4 = *(const float4*)&Sl[n0];
            float4 b4 = *(const float4*)&bl[n0];
            float4 o;
            o.x = rs*acc[nt][0] - mr*S4.x + b4.x;
            o.y = rs*acc[nt][1] - mr*S4.y + b4.y;
            o.z = rs*acc[nt][2] - mr*S4.z + b4.z;
            o.w = rs*acc[nt][3] - mr*S4.w + b4.w;
            if constexpr (!UD) {
                o.x = gelu_f(o.x); o.y = gelu_f(o.y);
                o.z = gelu_f(o.z); o.w = gelu_f(o.w);
            }
            uint2 pu = make_uint2(pkpair(o.x, o.y), pkpair(o.z, o.w));
            *(uint2*)(outB + row*256 + n0) = pu;
        }
    }
}

// ---------------- GEMM K=256 N=128 (bf16 A), fp32 out, persistent waves --------------
// Operand-swapped: lane cl owns output row t directly; no LDS transpose.
// EPI: 2 = acc+bias+resid; 3 = resid+acc+ud (ud pre-multiplied by dskip)
template<int EPI>
__global__ __launch_bounds__(1024, 4) void gemm2(
    const bf16* __restrict__ A,        // [BT,256]
    const bf16* __restrict__ Bt,       // [128][256]
    float* out,                        // [BT,128] (may alias resid, same-elem r-then-w)
    const float* __restrict__ bias,
    const float* resid,
    const bf16* __restrict__ ud)
{
    __shared__ bf16 Bs[128*264];       // 67584 B

    int tid = threadIdx.x;
    #pragma unroll
    for (int it = 0; it < 4; ++it) {
        int f = it*1024 + tid;
        int n = f >> 5, kk = (f & 31)*8;
        *(bf16x8*)&Bs[n*264 + kk] = *(const bf16x8*)(Bt + n*256 + kk);
    }
    __syncthreads();

    int wid = tid >> 6, lane = tid & 63;
    int quad = lane >> 4, cl = lane & 15;
    int s = blockIdx.x*16 + wid;
    size_t row = (size_t)s*16 + cl;

    bf16x8 af[8];
    #pragma unroll
    for (int ks = 0; ks < 8; ++ks)
        af[ks] = *(const bf16x8*)(A + row*256 + quad*8 + ks*32);

    f32x4 acc[8] = {};
    #pragma unroll
    for (int nt = 0; nt < 8; ++nt) {
        const bf16* wrp = &Bs[(nt*16 + cl)*264 + quad*8];
        #pragma unroll
        for (int ks = 0; ks < 8; ++ks)
            acc[nt] = __builtin_amdgcn_mfma_f32_16x16x32_bf16(
                          *(const bf16x8*)(wrp + ks*32), af[ks], acc[nt], 0, 0, 0);
    }

    #pragma unroll
    for (int nt = 0; nt < 8; ++nt) {
        int n0 = nt*16 + quad*4;
        size_t oidx = row*128 + n0;
        float4 rv = *(const float4*)(resid + oidx);
        float4 o;
        if (EPI == 2) {
            float4 bv = *(const float4*)(bias + n0);
            o.x = acc[nt][0] + bv.x + rv.x; o.y = acc[nt][1] + bv.y + rv.y;
            o.z = acc[nt][2] + bv.z + rv.z; o.w = acc[nt][3] + bv.w + rv.w;
        } else {
            ushort4 u4 = *(const ushort4*)(ud + oidx);
            o.x = rv.x + acc[nt][0] + bf2f(u4.x); o.y = rv.y + acc[nt][1] + bf2f(u4.y);
            o.z = rv.z + acc[nt][2] + bf2f(u4.z); o.w = rv.w + acc[nt][3] + bf2f(u4.w);
        }
        *(float4*)(out + oidx) = o;
    }
}

// ---------------- chunked scan on bf16-pair xs: x_t = a*x_{t-1} + Bu_t ---------------
__global__ __launch_bounds__(256) void scan_local(unsigned int* __restrict__ xs,
                                                  const float4* __restrict__ coefs,
                                                  float2* __restrict__ carry)
{
    int flat = blockIdx.x*256 + threadIdx.x;  // 2^18
    int n = flat & 127;
    int b = (flat >> 7) & 31;
    int c = flat >> 12;
    float4 cf = coefs[n];
    float2 a = make_float2(cf.x, cf.y);
    unsigned int* base = xs + ((size_t)(b*TSEQ + c*LC))*NST + n;
    float2 x = make_float2(0.f, 0.f);
    for (int j = 0; j < LC; ++j) {
        float2 v = upk(base[(size_t)j*NST]);
        x = make_float2(a.x*x.x - a.y*x.y + v.x, a.x*x.y + a.y*x.x + v.y);
        base[(size_t)j*NST] = pk(x);
    }
    carry[c*(BATCH*NST) + b*NST + n] = x;
}

__global__ void scan_carry(float2* __restrict__ carry, const float4* __restrict__ coefs)
{
    int flat = blockIdx.x*256 + threadIdx.x;  // 4096 = B*N
    int n = flat & 127;
    float4 cf = coefs[n];
    float2 aL = make_float2(cf.z, cf.w);
    float2 x = make_float2(0.f, 0.f);
    for (int c = 0; c < NCHK; ++c) {
        float2* p = carry + c*(BATCH*NST) + flat;
        float2 v = *p;
        *p = x;                                // exclusive prefix
        x = make_float2(aL.x*x.x - aL.y*x.y + v.x, aL.x*x.y + aL.y*x.x + v.y);
    }
}

__global__ __launch_bounds__(256) void scan_fix(unsigned int* __restrict__ xs,
                                                const float4* __restrict__ coefs,
                                                const float2* __restrict__ carry)
{
    int flat = blockIdx.x*256 + threadIdx.x;
    int n = flat & 127;
    int b = (flat >> 7) & 31;
    int c = flat >> 12;
    if (c == 0) return;
    float2 cin = carry[c*(BATCH*NST) + b*NST + n];
    float4 cf = coefs[n];
    float2 a = make_float2(cf.x, cf.y);
    unsigned int* base = xs + ((size_t)(b*TSEQ + c*LC))*NST + n;
    float2 p = a;
    for (int j = 0; j < LC; ++j) {
        float2 add = cmul2(p, cin);
        float2 v = upk(base[(size_t)j*NST]);
        base[(size_t)j*NST] = pk(make_float2(v.x + add.x, v.y + add.y));
        p = cmul2(p, a);
    }
}

// ---------------- conv1: fp32 in, implicit-im2col MFMA (operand-swapped), bf16 out ----
__global__ __launch_bounds__(256, 4) void conv1_mfma(
    const float* __restrict__ X,
    const bf16* __restrict__ wB,    // [128][640]
    const float* __restrict__ bias,
    bf16* __restrict__ out,         // [B*Lout][128]
    int Tin, int Lout)
{
    __shared__ bf16 As[128][72];
    __shared__ bf16 Bs[128][72];
    int tid  = threadIdx.x;
    int lane = tid & 63;
    int wave = tid >> 6;
    int wm = wave >> 1, wn = wave & 1;
    int quad = lane >> 4, cl = lane & 15;
    int row0 = blockIdx.x * 128;
    int b  = row0 / Lout;
    int l0 = row0 % Lout;
    const float* Xb = X + (size_t)b*Tin*128;

    f32x4 acc[4][4] = {};

    for (int k0 = 0; k0 < 640; k0 += 64) {
        int tap = k0 / 128;
        int icb = k0 % 128;
        #pragma unroll
        for (int it = 0; it < 8; ++it) {
            int idx = it*256 + tid;
            int r = idx >> 4, kof = (idx & 15) * 4;
            int t = 2*(l0 + r) - 2 + tap;
            uint2 h = make_uint2(0u, 0u);
            if (t >= 0 && t < Tin) {
                float4 f = *(const float4*)(Xb + (size_t)t*128 + icb + kof);
                h = make_uint2(pkpair(f.x, f.y), pkpair(f.z, f.w));
            }
            *(uint2*)&As[r][kof] = h;
        }
        #pragma unroll
        for (int it = 0; it < 4; ++it) {
            int idx = it*256 + tid;
            int n = idx >> 3, kof = (idx & 7) * 8;
            *(bf16x8*)&Bs[n][kof] = *(const bf16x8*)(wB + (size_t)n*640 + k0 + kof);
        }
        __syncthreads();
        #pragma unroll
        for (int kk = 0; kk < 64; kk += 32) {
            bf16x8 af[4], bfr[4];
            #pragma unroll
            for (int i = 0; i < 4; ++i)
                af[i] = *(const bf16x8*)&As[wm*64 + i*16 + cl][kk + quad*8];
            #pragma unroll
            for (int j = 0; j < 4; ++j)
                bfr[j] = *(const bf16x8*)&Bs[wn*64 + j*16 + cl][kk + quad*8];
            #pragma unroll
            for (int i = 0; i < 4; ++i)
                #pragma unroll
                for (int j = 0; j < 4; ++j)
                    acc[i][j] = __builtin_amdgcn_mfma_f32_16x16x32_bf16(
                                    bfr[j], af[i], acc[i][j], 0, 0, 0);
        }
        __syncthreads();
    }

    // D: col=cl -> output position l, rows quad*4+r -> channel. Direct uint2 stores.
    #pragma unroll
    for (int i = 0; i < 4; ++i) {
        int grow = row0 + wm*64 + i*16 + cl;
        #pragma unroll
        for (int j = 0; j < 4; ++j) {
            int gcol = wn*64 + j*16 + quad*4;
            float4 bv = *(const float4*)(bias + gcol);
            float4 t;
            t.x = fmaxf(acc[i][j][0] + bv.x, 0.f); t.y = fmaxf(acc[i][j][1] + bv.y, 0.f);
            t.z = fmaxf(acc[i][j][2] + bv.z, 0.f); t.w = fmaxf(acc[i][j][3] + bv.w, 0.f);
            uint2 pu = make_uint2(pkpair(t.x, t.y), pkpair(t.z, t.w));
            *(uint2*)(out + (size_t)grow*128 + gcol) = pu;
        }
    }
}

// ---------------- conv2 (bf16 in) + fused relu + avg pool (operand-swapped) ----------
// After swap: lane cl = position l within 16-window -> pool = shuffle-reduce over cl.
__global__ __launch_bounds__(256, 4) void conv2_pool(
    const bf16* __restrict__ X,     // [B][Tin][128]
    const bf16* __restrict__ wB,    // [128][640]
    const float* __restrict__ bias,
    float* __restrict__ outp,       // [B][128][64]
    int Tin, int Lout)
{
    __shared__ bf16 As[128][72];
    __shared__ bf16 Bs[128][72];
    int tid  = threadIdx.x;
    int lane = tid & 63;
    int wave = tid >> 6;
    int wm = wave >> 1, wn = wave & 1;
    int quad = lane >> 4, cl = lane & 15;
    int row0 = blockIdx.x * 128;
    int b  = row0 / Lout;
    int l0 = row0 % Lout;
    int d0 = l0 / 16;
    const bf16* Xb = X + (size_t)b*Tin*128;

    f32x4 acc[4][4] = {};

    for (int k0 = 0; k0 < 640; k0 += 64) {
        int tap = k0 / 128;
        int icb = k0 % 128;
        #pragma unroll
        for (int it = 0; it < 4; ++it) {
            int idx = it*256 + tid;
            int r = idx >> 3, kof = (idx & 7) * 8;
            int t = 2*(l0 + r) - 2 + tap;
            bf16x8 z = {0,0,0,0,0,0,0,0};
            if (t >= 0 && t < Tin) z = *(const bf16x8*)(Xb + (size_t)t*128 + icb + kof);
            *(bf16x8*)&As[r][kof] = z;
        }
        #pragma unroll
        for (int it = 0; it < 4; ++it) {
            int idx = it*256 + tid;
            int n = idx >> 3, kof = (idx & 7) * 8;
            *(bf16x8*)&Bs[n][kof] = *(const bf16x8*)(wB + (size_t)n*640 + k0 + kof);
        }
        __syncthreads();
        #pragma unroll
        for (int kk = 0; kk < 64; kk += 32) {
            bf16x8 af[4], bfr[4];
            #pragma unroll
            for (int i = 0; i < 4; ++i)
                af[i] = *(const bf16x8*)&As[wm*64 + i*16 + cl][kk + quad*8];
            #pragma unroll
            for (int j = 0; j < 4; ++j)
                bfr[j] = *(const bf16x8*)&Bs[wn*64 + j*16 + cl][kk + quad*8];
            #pragma unroll
            for (int i = 0; i < 4; ++i)
                #pragma unroll
                for (int j = 0; j < 4; ++j)
                    acc[i][j] = __builtin_amdgcn_mfma_f32_16x16x32_bf16(
                                    bfr[j], af[i], acc[i][j], 0, 0, 0);
        }
        __syncthreads();
    }

    // lane (quad,cl): channels gcol..+3 (rows), position l = group + cl (col).
    #pragma unroll
    for (int j = 0; j < 4; ++j) {
        int gcol = wn*64 + j*16 + quad*4;
        float4 bv = *(const float4*)(bias + gcol);
        #pragma unroll
        for (int i = 0; i < 4; ++i) {
            float4 sp;
            sp.x = fmaxf(acc[i][j][0] + bv.x, 0.f);
            sp.y = fmaxf(acc[i][j][1] + bv.y, 0.f);
            sp.z = fmaxf(acc[i][j][2] + bv.z, 0.f);
            sp.w = fmaxf(acc[i][j][3] + bv.w, 0.f);
            #pragma unroll
            for (int off = 1; off <= 8; off <<= 1) {
                sp.x += __shfl_xor(sp.x, off);
                sp.y += __shfl_xor(sp.y, off);
                sp.z += __shfl_xor(sp.z, off);
                sp.w += __shfl_xor(sp.w, off);
            }
            if (cl == 0) {
                int d = d0 + wm*4 + i;
                float* op = outp + (size_t)b*8192 + (size_t)gcol*64 + d;
                op[0]   = sp.x * (1.f/16.f);
                op[64]  = sp.y * (1.f/16.f);
                op[128] = sp.z * (1.f/16.f);
                op[192] = sp.w * (1.f/16.f);
            }
        }
    }
}

extern "C" void kernel_launch(void* const* d_in, const int* in_sizes, int n_in,
                              void* d_out, int out_size, void* d_ws, size_t ws_size,
                              hipStream_t stream)
{
    (void)in_sizes; (void)n_in; (void)out_size; (void)ws_size;
    const float* x_in    = (const float*)d_in[0];
    const float* ln1_g   = (const float*)d_in[1];
    const float* ln1_b   = (const float*)d_in[2];
    const float* ln2_g   = (const float*)d_in[3];
    const float* ln2_b   = (const float*)d_in[4];
    const float* Lam_re  = (const float*)d_in[5];
    const float* Lam_im  = (const float*)d_in[6];
    const float* B_re    = (const float*)d_in[7];
    const float* B_im    = (const float*)d_in[8];
    const float* C_re    = (const float*)d_in[9];
    const float* C_im    = (const float*)d_in[10];
    const float* D_skip  = (const float*)d_in[11];
    const float* log_step= (const float*)d_in[12];
    const float* W1      = (const float*)d_in[13];
    const float* b1      = (const float*)d_in[14];
    const float* W2      = (const float*)d_in[15];
    const float* b2      = (const float*)d_in[16];
    const float* conv1_w = (const float*)d_in[17];
    const float* conv1_b = (const float*)d_in[18];
    const float* conv2_w = (const float*)d_in[19];
    const float* conv2_b = (const float*)d_in[20];
    float* out = (float*)d_out;

    // Workspace (~188 MB): X fp32 64MB | Cbuf bf16 [BT,256] 64MB | Abf(ud) bf16 32MB
    //                      | conv1out bf16 16MB | params+carry ~3MB
    char* ws = (char*)d_ws;
    float* X      = (float*)(ws);
    bf16*  Cbuf   = (bf16*) (ws + (size_t)67108864);
    bf16*  Abf    = (bf16*) (ws + (size_t)134217728);
    bf16*  Cv1    = (bf16*) (ws + (size_t)167772160);
    char*  wreg   = ws + (size_t)184549376;
    bf16*   Wbu_bf = (bf16*)(wreg);                  // 131072
    bf16*   Wc_bf  = (bf16*)(wreg + 131072);         // 131072
    bf16*   W1_bf  = (bf16*)(wreg + 262144);         // 131072
    bf16*   W2_bf  = (bf16*)(wreg + 393216);         // 131072
    float*  Sb     = (float*)(wreg + 524288);        // 2048
    float*  biasb  = (float*)(wreg + 526336);        // 2048
    float*  S1     = (float*)(wreg + 528384);        // 2048
    float*  bias1p = (float*)(wreg + 530432);        // 2048
    float*  gd     = (float*)(wreg + 532480);        // 1024
    float*  bd     = (float*)(wreg + 533504);        // 1024
    float4* coefs  = (float4*)(wreg + 534528);       // 4096
    bf16*   wB1    = (bf16*)(wreg + 538624);         // 163840
    bf16*   wB2    = (bf16*)(wreg + 702464);         // 163840
    float2* carry  = (float2*)(wreg + 866304);       // 2 MB

    prep_s5<<<2, 128, 0, stream>>>(Lam_re, Lam_im, B_re, B_im, C_re, C_im, log_step,
                                   ln1_g, ln1_b, D_skip,
                                   Wbu_bf, Wc_bf, Sb, biasb, gd, bd, coefs);
    prep_w1<<<2, 256, 0, stream>>>(W1, b1, ln2_g, ln2_b, W1_bf, S1, bias1p);
    prep_w2<<<2, 128, 0, stream>>>(W2, W2_bf);
    prep_wB<<<640, 256, 0, stream>>>(conv1_w, conv2_w, wB1, wB2);

    for (int i = 0; i < 2; ++i) {
        const float* src = (i == 0) ? x_in : X;     // layer input / residual
        // ---- S5 sub-block: fused LN+Wbu (writes Bu + ud), scan, Wc+resid+ud ----
        lngemm<1><<<512, 1024, 0, stream>>>(
            src, Wbu_bf + (size_t)i*32768, Sb + i*256, biasb + i*256,
            Cbuf, gd + i*128, bd + i*128, Abf);
        scan_local<<<1024, 256, 0, stream>>>((unsigned int*)Cbuf, coefs + i*NST, carry);
        scan_carry<<<16, 256, 0, stream>>>(carry, coefs + i*NST);
        scan_fix<<<1024, 256, 0, stream>>>((unsigned int*)Cbuf, coefs + i*NST, carry);
        gemm2<3><<<512, 1024, 0, stream>>>(
            Cbuf, Wc_bf + (size_t)i*32768, X, nullptr, src, Abf);
        // ---- MLP sub-block: fused LN+W1+gelu, W2+bias+resid ----
        lngemm<0><<<512, 1024, 0, stream>>>(
            X, W1_bf + (size_t)i*32768, S1 + i*256, bias1p + i*256,
            Cbuf, nullptr, nullptr, nullptr);
        gemm2<2><<<512, 1024, 0, stream>>>(
            Cbuf, W2_bf + (size_t)i*32768, X, b2 + i*HD, X, nullptr);
    }

    // ---- head: conv1 (X -> bf16) -> conv2+pool (-> d_out) ----
    conv1_mfma<<<512, 256, 0, stream>>>(X, wB1, conv1_b, Cv1, 4096, 2048);
    conv2_pool<<<256, 256, 0, stream>>>(Cv1, wB2, conv2_b, out, 2048, 1024);
}

// Round 10
// 596.512 us; speedup vs baseline: 1.7309x; 1.1324x over previous
//
#include <hip/hip_runtime.h>
#include <math.h>

#define BATCH 32
#define TSEQ  4096
#define HD    128
#define NST   128
#define BT    (BATCH*TSEQ)     // 131072
#define LC    64               // scan chunk length
#define NCHK  (TSEQ/LC)        // 64 chunks

typedef unsigned short bf16;
typedef __attribute__((ext_vector_type(8))) short bf16x8;   // 8 bf16 = 4 VGPRs (MFMA A/B frag)
typedef __attribute__((ext_vector_type(4))) float f32x4;    // MFMA C/D frag

__device__ inline float bf2f(bf16 s) {
    union { unsigned int u; float f; } v; v.u = ((unsigned int)s) << 16; return v.f;
}
__device__ inline bf16 f2bf(float f) {
    union { float f; unsigned int u; } v; v.f = f;
    unsigned int u = v.u;
    unsigned int r = (u + 0x7fffu + ((u >> 16) & 1u)) >> 16;
    return (bf16)r;
}
// pack two f32 -> bf16 pair (round-half-up) in ~3 VALU via v_perm
__device__ inline unsigned int pkpair(float lo, float hi) {
    union { float f; unsigned int u; } a, b;
    a.f = lo; b.f = hi;
    return __builtin_amdgcn_perm(b.u + 0x8000u, a.u + 0x8000u, 0x07060302u);
}
__device__ inline bf16x8 pack8f(float4 f0, float4 f1) {
    union { bf16x8 v; unsigned int u[4]; } t;
    t.u[0] = pkpair(f0.x, f0.y);
    t.u[1] = pkpair(f0.z, f0.w);
    t.u[2] = pkpair(f1.x, f1.y);
    t.u[3] = pkpair(f1.z, f1.w);
    return t.v;
}
__device__ inline float2 cmul2(float2 a, float2 b) {
    return make_float2(a.x*b.x - a.y*b.y, a.x*b.y + a.y*b.x);
}
// tanh-form gelu: max |diff vs exact erf-gelu| ~1e-3, under bf16 noise here
__device__ inline float gelu_f(float x) {
    float u = x*(0.7978845608f + 0.0356774081f*x*x);
    return __fdividef(x, 1.f + __expf(-2.f*u));
}
__device__ inline float2 upk(unsigned int w) {     // bf16 pair -> fp32 pair
    union { unsigned int u; float f; } a, b;
    a.u = w << 16; b.u = w & 0xffff0000u;
    return make_float2(a.f, b.f);
}
__device__ inline unsigned int pk(float2 x) { return pkpair(x.x, x.y); }

// ---------------- S5 param prep: g-folded W'bu, S/bias corrections, Wc, gd/bd, coefs ----
__global__ void prep_s5(const float* __restrict__ Lam_re, const float* __restrict__ Lam_im,
                        const float* __restrict__ B_re,  const float* __restrict__ B_im,
                        const float* __restrict__ C_re,  const float* __restrict__ C_im,
                        const float* __restrict__ log_step,
                        const float* __restrict__ ln1_g, const float* __restrict__ ln1_b,
                        const float* __restrict__ D_skip,
                        bf16* __restrict__ Wbu_bf,  // [2][256][128], row 2n=Re 2n+1=Im, g-folded
                        bf16* __restrict__ Wc_bf,   // [2][128][256], col 2n=2Cre 2n+1=-2Cim
                        float* __restrict__ Sb, float* __restrict__ biasb,   // [2][256]
                        float* __restrict__ gd, float* __restrict__ bd,      // [2][128]
                        float4* __restrict__ coefs)
{
    int i = blockIdx.x, n = threadIdx.x;
    int in = i*NST + n;
    float lr = Lam_re[in], li = Lam_im[in];
    float dt = expf(log_step[in]);
    float ea = expf(lr*dt);
    float ar = ea*cosf(li*dt), ai = ea*sinf(li*dt);
    float xx = ar - 1.f, yy = ai;
    float den = lr*lr + li*li;
    float sr = (xx*lr + yy*li)/den;
    float si = (yy*lr - xx*li)/den;
    float2 p = make_float2(ar, ai);
    #pragma unroll
    for (int q = 0; q < 6; ++q) p = cmul2(p, p);   // a^64
    coefs[in] = make_float4(ar, ai, p.x, p.y);

    const float* g  = ln1_g + i*HD;
    const float* bb = ln1_b + i*HD;
    const float* br = B_re + (size_t)in*HD;
    const float* bi = B_im + (size_t)in*HD;
    bf16* wb = Wbu_bf + (size_t)i*256*128;
    float s_re = 0.f, s_im = 0.f, bc_re = 0.f, bc_im = 0.f;
    for (int h = 0; h < HD; ++h) {
        float wre = sr*br[h] - si*bi[h];
        float wim = sr*bi[h] + si*br[h];
        bf16 wrb = f2bf(g[h]*wre), wib = f2bf(g[h]*wim);
        wb[(2*n)*128 + h]   = wrb;
        wb[(2*n+1)*128 + h] = wib;
        s_re += bf2f(wrb); s_im += bf2f(wib);
        bc_re += bb[h]*wre; bc_im += bb[h]*wim;
    }
    Sb[i*256 + 2*n] = s_re;     Sb[i*256 + 2*n+1] = s_im;
    biasb[i*256 + 2*n] = bc_re; biasb[i*256 + 2*n+1] = bc_im;

    const float* cr = C_re + (size_t)i*HD*NST;
    const float* ci = C_im + (size_t)i*HD*NST;
    bf16* wc = Wc_bf + (size_t)i*128*256;
    for (int h = 0; h < HD; ++h) {
        wc[h*256 + 2*n]   = f2bf( 2.f * cr[h*NST + n]);
        wc[h*256 + 2*n+1] = f2bf(-2.f * ci[h*NST + n]);
    }
    gd[i*HD + n] = g[n]*D_skip[i*HD + n];
    bd[i*HD + n] = bb[n]*D_skip[i*HD + n];
}

// W1 -> g2-folded bf16 [f][h] + S1/bias1' (bias1' includes b1)
__global__ void prep_w1(const float* __restrict__ W1, const float* __restrict__ b1,
                        const float* __restrict__ ln2_g, const float* __restrict__ ln2_b,
                        bf16* __restrict__ W1_bf, float* __restrict__ S1,
                        float* __restrict__ bias1p)
{
    int i = blockIdx.x, f = threadIdx.x;       // f in [0,256)
    const float* g  = ln2_g + i*HD;
    const float* bb = ln2_b + i*HD;
    bf16* w = W1_bf + (size_t)i*256*128;
    float S = 0.f, bi_ = b1[i*256 + f];
    for (int h = 0; h < HD; ++h) {
        float wv = W1[(size_t)i*32768 + h*256 + f];
        bf16 wbv = f2bf(g[h]*wv);
        w[f*128 + h] = wbv;
        S += bf2f(wbv);
        bi_ += bb[h]*wv;
    }
    S1[i*256 + f] = S;
    bias1p[i*256 + f] = bi_;
}

// W2 -> plain bf16 transposed [h][f]
__global__ void prep_w2(const float* __restrict__ W2, bf16* __restrict__ W2_bf)
{
    int i = blockIdx.x, h = threadIdx.x;       // h in [0,128)
    bf16* w = W2_bf + (size_t)i*128*256;
    for (int f = 0; f < 256; ++f)
        w[h*256 + f] = f2bf(W2[(size_t)i*32768 + f*128 + h]);
}

// conv weights [c][ic][tap] -> bf16 [c][tap*128+ic]
__global__ void prep_wB(const float* __restrict__ w1, const float* __restrict__ w2,
                        bf16* __restrict__ wB1, bf16* __restrict__ wB2)
{
    int idx = blockIdx.x*256 + threadIdx.x;
    if (idx >= 163840) return;
    const float* w = (idx < 81920) ? w1 : w2;
    bf16* wb       = (idx < 81920) ? wB1 : wB2;
    int r   = idx % 81920;
    int c   = r / 640;
    int tap = (r % 640) / 128;
    int ic  = r % 128;
    wb[r] = f2bf(w[(c*128 + ic)*5 + tap]);
}

// ---------------- fused LN + GEMM (K=128, N=256), bf16 out, persistent waves ----------
// Operand-swapped MFMA: lane cl owns output row t = s*16+cl directly.
// UD=1: stores per-row (mu,rs) to munrs (ud recomputed downstream in gemm2). UD=0: gelu.
template<int UD, typename TA>
__global__ __launch_bounds__(1024, 4) void lngemm(
    const TA* __restrict__ A,          // [BT,128] fp32 or bf16
    const bf16* __restrict__ Bt,       // [256][128] g-folded
    const float* __restrict__ Svec, const float* __restrict__ bvec,  // [256]
    bf16* __restrict__ outB,           // [BT,256]
    float2* __restrict__ munrs)        // [BT], UD=1 only
{
    __shared__ bf16 Bs[256*136];       // 69632 B (+8 pad per row)
    __shared__ float Sl[256], bl[256];

    int tid = threadIdx.x;
    #pragma unroll
    for (int it = 0; it < 4; ++it) {
        int f = it*1024 + tid;
        int n = f >> 4, kk = (f & 15)*8;
        *(bf16x8*)&Bs[n*136 + kk] = *(const bf16x8*)(Bt + n*128 + kk);
    }
    if (tid < 256) { Sl[tid] = Svec[tid]; bl[tid] = bvec[tid]; }
    __syncthreads();

    int wid = tid >> 6, lane = tid & 63;
    int quad = lane >> 4, cl = lane & 15;
    int s = blockIdx.x*16 + wid;                  // strip [0,8192)
    size_t row = (size_t)s*16 + cl;

    // streaming load: stats + bf16 frags (no fp32 row kept live)
    bf16x8 af[4];
    float sm = 0.f, sq = 0.f;
    if constexpr (sizeof(TA) == 2) {
        const bf16* ar = (const bf16*)A + row*128;
        #pragma unroll
        for (int ks = 0; ks < 4; ++ks) {
            af[ks] = *(const bf16x8*)(ar + quad*8 + ks*32);
            union { bf16x8 v; unsigned int u[4]; } aa; aa.v = af[ks];
            #pragma unroll
            for (int jp = 0; jp < 4; ++jp) {
                float2 vv = upk(aa.u[jp]);
                sm += vv.x + vv.y;
                sq += vv.x*vv.x + vv.y*vv.y;
            }
        }
    } else {
        const float* ar = (const float*)A + row*128;
        #pragma unroll
        for (int ks = 0; ks < 4; ++ks) {
            float4 f0 = *(const float4*)(ar + quad*8 + ks*32);
            float4 f1 = *(const float4*)(ar + quad*8 + ks*32 + 4);
            sm += f0.x + f0.y + f0.z + f0.w + f1.x + f1.y + f1.z + f1.w;
            sq += f0.x*f0.x + f0.y*f0.y + f0.z*f0.z + f0.w*f0.w
                + f1.x*f1.x + f1.y*f1.y + f1.z*f1.z + f1.w*f1.w;
            af[ks] = pack8f(f0, f1);
        }
    }
    // full-row stats via cross-quad reduce (4 quads of same cl share a row)
    sm += __shfl_xor(sm, 16); sm += __shfl_xor(sm, 32);
    sq += __shfl_xor(sq, 16); sq += __shfl_xor(sq, 32);
    float mu = sm * (1.f/128.f);
    float rs = rsqrtf(sq*(1.f/128.f) - mu*mu + 1e-5f);
    float mr = mu*rs;

    if constexpr (UD) {
        if (quad == 0) munrs[row] = make_float2(mu, rs);
    }

    #pragma unroll
    for (int half = 0; half < 2; ++half) {
        f32x4 acc[8] = {};
        #pragma unroll
        for (int nt = 0; nt < 8; ++nt) {
            const bf16* wrp = &Bs[((half*8+nt)*16 + cl)*136 + quad*8];
            #pragma unroll
            for (int ks = 0; ks < 4; ++ks)
                acc[nt] = __builtin_amdgcn_mfma_f32_16x16x32_bf16(
                              *(const bf16x8*)(wrp + ks*32), af[ks], acc[nt], 0, 0, 0);
        }
        // D: col=cl -> t=row, rows quad*4+r -> n within 16-group. Direct store.
        #pragma unroll
        for (int nt = 0; nt < 8; ++nt) {
            int n0 = (half*8+nt)*16 + quad*4;
            float4 S4 = *(const float4*)&Sl[n0];
            float4 b4 = *(const float4*)&bl[n0];
            float4 o;
            o.x = rs*acc[nt][0] - mr*S4.x + b4.x;
            o.y = rs*acc[nt][1] - mr*S4.y + b4.y;
            o.z = rs*acc[nt][2] - mr*S4.z + b4.z;
            o.w = rs*acc[nt][3] - mr*S4.w + b4.w;
            if constexpr (!UD) {
                o.x = gelu_f(o.x); o.y = gelu_f(o.y);
                o.z = gelu_f(o.z); o.w = gelu_f(o.w);
            }
            uint2 pu = make_uint2(pkpair(o.x, o.y), pkpair(o.z, o.w));
            *(uint2*)(outB + row*256 + n0) = pu;
        }
    }
}

// ---------------- GEMM K=256 N=128 (bf16 A), bf16 out, persistent waves --------------
// Operand-swapped; lane cl owns output row t directly.
// EPI=2: out = acc + bias + resid.  EPI=3: out = resid + acc + (resid-mu)*rs*gd + bd.
template<int EPI, typename TR>
__global__ __launch_bounds__(1024, 4) void gemm2(
    const bf16* __restrict__ A,        // [BT,256]
    const bf16* __restrict__ Bt,       // [128][256]
    bf16* out,                         // [BT,128] (may alias resid, same-elem r-then-w)
    const float* __restrict__ bias,    // EPI=2
    const TR* resid,                   // [BT,128]
    const float2* __restrict__ munrs,  // EPI=3
    const float* __restrict__ gdp, const float* __restrict__ bdp)   // EPI=3
{
    __shared__ bf16 Bs[128*264];       // 67584 B
    __shared__ float gdl[128], bdl[128];

    int tid = threadIdx.x;
    #pragma unroll
    for (int it = 0; it < 4; ++it) {
        int f = it*1024 + tid;
        int n = f >> 5, kk = (f & 31)*8;
        *(bf16x8*)&Bs[n*264 + kk] = *(const bf16x8*)(Bt + n*256 + kk);
    }
    if constexpr (EPI == 3) {
        if (tid < 128) { gdl[tid] = gdp[tid]; bdl[tid] = bdp[tid]; }
    } else {
        if (tid < 128) { gdl[tid] = bias[tid]; }
    }
    __syncthreads();

    int wid = tid >> 6, lane = tid & 63;
    int quad = lane >> 4, cl = lane & 15;
    int s = blockIdx.x*16 + wid;
    size_t row = (size_t)s*16 + cl;

    float mu = 0.f, rs = 0.f;
    if constexpr (EPI == 3) { float2 m2 = munrs[row]; mu = m2.x; rs = m2.y; }

    bf16x8 af[8];
    #pragma unroll
    for (int ks = 0; ks < 8; ++ks)
        af[ks] = *(const bf16x8*)(A + row*256 + quad*8 + ks*32);

    f32x4 acc[8] = {};
    #pragma unroll
    for (int nt = 0; nt < 8; ++nt) {
        const bf16* wrp = &Bs[(nt*16 + cl)*264 + quad*8];
        #pragma unroll
        for (int ks = 0; ks < 8; ++ks)
            acc[nt] = __builtin_amdgcn_mfma_f32_16x16x32_bf16(
                          *(const bf16x8*)(wrp + ks*32), af[ks], acc[nt], 0, 0, 0);
    }

    #pragma unroll
    for (int nt = 0; nt < 8; ++nt) {
        int n0 = nt*16 + quad*4;
        size_t oidx = row*128 + n0;
        float4 rv;
        if constexpr (sizeof(TR) == 2) {
            ushort4 u4 = *(const ushort4*)((const bf16*)resid + oidx);
            rv = make_float4(bf2f(u4.x), bf2f(u4.y), bf2f(u4.z), bf2f(u4.w));
        } else {
            rv = *(const float4*)((const float*)resid + oidx);
        }
        float4 o;
        if constexpr (EPI == 2) {
            float4 bv = *(const float4*)&gdl[n0];
            o.x = acc[nt][0] + bv.x + rv.x; o.y = acc[nt][1] + bv.y + rv.y;
            o.z = acc[nt][2] + bv.z + rv.z; o.w = acc[nt][3] + bv.w + rv.w;
        } else {
            float4 g4 = *(const float4*)&gdl[n0];
            float4 b4 = *(const float4*)&bdl[n0];
            o.x = rv.x + acc[nt][0] + (rv.x - mu)*rs*g4.x + b4.x;
            o.y = rv.y + acc[nt][1] + (rv.y - mu)*rs*g4.y + b4.y;
            o.z = rv.z + acc[nt][2] + (rv.z - mu)*rs*g4.z + b4.z;
            o.w = rv.w + acc[nt][3] + (rv.w - mu)*rs*g4.w + b4.w;
        }
        uint2 pu = make_uint2(pkpair(o.x, o.y), pkpair(o.z, o.w));
        *(uint2*)(out + oidx) = pu;
    }
}

// ---------------- chunked scan on bf16-pair xs: x_t = a*x_{t-1} + Bu_t ---------------
__global__ __launch_bounds__(256) void scan_local(unsigned int* __restrict__ xs,
                                                  const float4* __restrict__ coefs,
                                                  float2* __restrict__ carry)
{
    int flat = blockIdx.x*256 + threadIdx.x;  // 2^18
    int n = flat & 127;
    int b = (flat >> 7) & 31;
    int c = flat >> 12;
    float4 cf = coefs[n];
    float2 a = make_float2(cf.x, cf.y);
    unsigned int* base = xs + ((size_t)(b*TSEQ + c*LC))*NST + n;
    float2 x = make_float2(0.f, 0.f);
    for (int j = 0; j < LC; ++j) {
        float2 v = upk(base[(size_t)j*NST]);
        x = make_float2(a.x*x.x - a.y*x.y + v.x, a.x*x.y + a.y*x.x + v.y);
        base[(size_t)j*NST] = pk(x);
    }
    carry[c*(BATCH*NST) + b*NST + n] = x;
}

__global__ void scan_carry(float2* __restrict__ carry, const float4* __restrict__ coefs)
{
    int flat = blockIdx.x*256 + threadIdx.x;  // 4096 = B*N
    int n = flat & 127;
    float4 cf = coefs[n];
    float2 aL = make_float2(cf.z, cf.w);
    float2 x = make_float2(0.f, 0.f);
    for (int c = 0; c < NCHK; ++c) {
        float2* p = carry + c*(BATCH*NST) + flat;
        float2 v = *p;
        *p = x;                                // exclusive prefix
        x = make_float2(aL.x*x.x - aL.y*x.y + v.x, aL.x*x.y + aL.y*x.x + v.y);
    }
}

__global__ __launch_bounds__(256) void scan_fix(unsigned int* __restrict__ xs,
                                                const float4* __restrict__ coefs,
                                                const float2* __restrict__ carry)
{
    int flat = blockIdx.x*256 + threadIdx.x;
    int n = flat & 127;
    int b = (flat >> 7) & 31;
    int c = flat >> 12;
    if (c == 0) return;
    float2 cin = carry[c*(BATCH*NST) + b*NST + n];
    float4 cf = coefs[n];
    float2 a = make_float2(cf.x, cf.y);
    unsigned int* base = xs + ((size_t)(b*TSEQ + c*LC))*NST + n;
    float2 p = a;
    for (int j = 0; j < LC; ++j) {
        float2 add = cmul2(p, cin);
        float2 v = upk(base[(size_t)j*NST]);
        base[(size_t)j*NST] = pk(make_float2(v.x + add.x, v.y + add.y));
        p = cmul2(p, a);
    }
}

// ---------------- conv1: bf16 in, implicit-im2col MFMA (operand-swapped), bf16 out ----
__global__ __launch_bounds__(256, 4) void conv1_mfma(
    const bf16* __restrict__ X,
    const bf16* __restrict__ wB,    // [128][640]
    const float* __restrict__ bias,
    bf16* __restrict__ out,         // [B*Lout][128]
    int Tin, int Lout)
{
    __shared__ bf16 As[128][72];
    __shared__ bf16 Bs[128][72];
    int tid  = threadIdx.x;
    int lane = tid & 63;
    int wave = tid >> 6;
    int wm = wave >> 1, wn = wave & 1;
    int quad = lane >> 4, cl = lane & 15;
    int row0 = blockIdx.x * 128;
    int b  = row0 / Lout;
    int l0 = row0 % Lout;
    const bf16* Xb = X + (size_t)b*Tin*128;

    f32x4 acc[4][4] = {};

    for (int k0 = 0; k0 < 640; k0 += 64) {
        int tap = k0 / 128;
        int icb = k0 % 128;
        #pragma unroll
        for (int it = 0; it < 4; ++it) {
            int idx = it*256 + tid;
            int r = idx >> 3, kof = (idx & 7) * 8;
            int t = 2*(l0 + r) - 2 + tap;
            bf16x8 z = {0,0,0,0,0,0,0,0};
            if (t >= 0 && t < Tin) z = *(const bf16x8*)(Xb + (size_t)t*128 + icb + kof);
            *(bf16x8*)&As[r][kof] = z;
        }
        #pragma unroll
        for (int it = 0; it < 4; ++it) {
            int idx = it*256 + tid;
            int n = idx >> 3, kof = (idx & 7) * 8;
            *(bf16x8*)&Bs[n][kof] = *(const bf16x8*)(wB + (size_t)n*640 + k0 + kof);
        }
        __syncthreads();
        #pragma unroll
        for (int kk = 0; kk < 64; kk += 32) {
            bf16x8 af[4], bfr[4];
            #pragma unroll
            for (int i = 0; i < 4; ++i)
                af[i] = *(const bf16x8*)&As[wm*64 + i*16 + cl][kk + quad*8];
            #pragma unroll
            for (int j = 0; j < 4; ++j)
                bfr[j] = *(const bf16x8*)&Bs[wn*64 + j*16 + cl][kk + quad*8];
            #pragma unroll
            for (int i = 0; i < 4; ++i)
                #pragma unroll
                for (int j = 0; j < 4; ++j)
                    acc[i][j] = __builtin_amdgcn_mfma_f32_16x16x32_bf16(
                                    bfr[j], af[i], acc[i][j], 0, 0, 0);
        }
        __syncthreads();
    }

    // D: col=cl -> output position l, rows quad*4+r -> channel. Direct uint2 stores.
    #pragma unroll
    for (int i = 0; i < 4; ++i) {
        int grow = row0 + wm*64 + i*16 + cl;
        #pragma unroll
        for (int j = 0; j < 4; ++j) {
            int gcol = wn*64 + j*16 + quad*4;
            float4 bv = *(const float4*)(bias + gcol);
            float4 t;
            t.x = fmaxf(acc[i][j][0] + bv.x, 0.f); t.y = fmaxf(acc[i][j][1] + bv.y, 0.f);
            t.z = fmaxf(acc[i][j][2] + bv.z, 0.f); t.w = fmaxf(acc[i][j][3] + bv.w, 0.f);
            uint2 pu = make_uint2(pkpair(t.x, t.y), pkpair(t.z, t.w));
            *(uint2*)(out + (size_t)grow*128 + gcol) = pu;
        }
    }
}

// ---------------- conv2 (bf16 in) + fused relu + avg pool (operand-swapped) ----------
__global__ __launch_bounds__(256, 4) void conv2_pool(
    const bf16* __restrict__ X,     // [B][Tin][128]
    const bf16* __restrict__ wB,    // [128][640]
    const float* __restrict__ bias,
    float* __restrict__ outp,       // [B][128][64]
    int Tin, int Lout)
{
    __shared__ bf16 As[128][72];
    __shared__ bf16 Bs[128][72];
    int tid  = threadIdx.x;
    int lane = tid & 63;
    int wave = tid >> 6;
    int wm = wave >> 1, wn = wave & 1;
    int quad = lane >> 4, cl = lane & 15;
    int row0 = blockIdx.x * 128;
    int b  = row0 / Lout;
    int l0 = row0 % Lout;
    int d0 = l0 / 16;
    const bf16* Xb = X + (size_t)b*Tin*128;

    f32x4 acc[4][4] = {};

    for (int k0 = 0; k0 < 640; k0 += 64) {
        int tap = k0 / 128;
        int icb = k0 % 128;
        #pragma unroll
        for (int it = 0; it < 4; ++it) {
            int idx = it*256 + tid;
            int r = idx >> 3, kof = (idx & 7) * 8;
            int t = 2*(l0 + r) - 2 + tap;
            bf16x8 z = {0,0,0,0,0,0,0,0};
            if (t >= 0 && t < Tin) z = *(const bf16x8*)(Xb + (size_t)t*128 + icb + kof);
            *(bf16x8*)&As[r][kof] = z;
        }
        #pragma unroll
        for (int it = 0; it < 4; ++it) {
            int idx = it*256 + tid;
            int n = idx >> 3, kof = (idx & 7) * 8;
            *(bf16x8*)&Bs[n][kof] = *(const bf16x8*)(wB + (size_t)n*640 + k0 + kof);
        }
        __syncthreads();
        #pragma unroll
        for (int kk = 0; kk < 64; kk += 32) {
            bf16x8 af[4], bfr[4];
            #pragma unroll
            for (int i = 0; i < 4; ++i)
                af[i] = *(const bf16x8*)&As[wm*64 + i*16 + cl][kk + quad*8];
            #pragma unroll
            for (int j = 0; j < 4; ++j)
                bfr[j] = *(const bf16x8*)&Bs[wn*64 + j*16 + cl][kk + quad*8];
            #pragma unroll
            for (int i = 0; i < 4; ++i)
                #pragma unroll
                for (int j = 0; j < 4; ++j)
                    acc[i][j] = __builtin_amdgcn_mfma_f32_16x16x32_bf16(
                                    bfr[j], af[i], acc[i][j], 0, 0, 0);
        }
        __syncthreads();
    }

    // lane (quad,cl): channels gcol..+3 (rows), position l = group + cl (col).
    #pragma unroll
    for (int j = 0; j < 4; ++j) {
        int gcol = wn*64 + j*16 + quad*4;
        float4 bv = *(const float4*)(bias + gcol);
        #pragma unroll
        for (int i = 0; i < 4; ++i) {
            float4 sp;
            sp.x = fmaxf(acc[i][j][0] + bv.x, 0.f);
            sp.y = fmaxf(acc[i][j][1] + bv.y, 0.f);
            sp.z = fmaxf(acc[i][j][2] + bv.z, 0.f);
            sp.w = fmaxf(acc[i][j][3] + bv.w, 0.f);
            #pragma unroll
            for (int off = 1; off <= 8; off <<= 1) {
                sp.x += __shfl_xor(sp.x, off);
                sp.y += __shfl_xor(sp.y, off);
                sp.z += __shfl_xor(sp.z, off);
                sp.w += __shfl_xor(sp.w, off);
            }
            if (cl == 0) {
                int d = d0 + wm*4 + i;
                float* op = outp + (size_t)b*8192 + (size_t)gcol*64 + d;
                op[0]   = sp.x * (1.f/16.f);
                op[64]  = sp.y * (1.f/16.f);
                op[128] = sp.z * (1.f/16.f);
                op[192] = sp.w * (1.f/16.f);
            }
        }
    }
}

extern "C" void kernel_launch(void* const* d_in, const int* in_sizes, int n_in,
                              void* d_out, int out_size, void* d_ws, size_t ws_size,
                              hipStream_t stream)
{
    (void)in_sizes; (void)n_in; (void)out_size; (void)ws_size;
    const float* x_in    = (const float*)d_in[0];
    const float* ln1_g   = (const float*)d_in[1];
    const float* ln1_b   = (const float*)d_in[2];
    const float* ln2_g   = (const float*)d_in[3];
    const float* ln2_b   = (const float*)d_in[4];
    const float* Lam_re  = (const float*)d_in[5];
    const float* Lam_im  = (const float*)d_in[6];
    const float* B_re    = (const float*)d_in[7];
    const float* B_im    = (const float*)d_in[8];
    const float* C_re    = (const float*)d_in[9];
    const float* C_im    = (const float*)d_in[10];
    const float* D_skip  = (const float*)d_in[11];
    const float* log_step= (const float*)d_in[12];
    const float* W1      = (const float*)d_in[13];
    const float* b1      = (const float*)d_in[14];
    const float* W2      = (const float*)d_in[15];
    const float* b2      = (const float*)d_in[16];
    const float* conv1_w = (const float*)d_in[17];
    const float* conv1_b = (const float*)d_in[18];
    const float* conv2_w = (const float*)d_in[19];
    const float* conv2_b = (const float*)d_in[20];
    float* out = (float*)d_out;

    // Workspace (~120 MB): Xbf bf16 32MB | Cbuf bf16 [BT,256] 64MB | Cv1 bf16 16MB
    //                      | munrs 1MB | params+carry ~3MB
    char* ws = (char*)d_ws;
    bf16*   Xbf    = (bf16*) (ws);
    bf16*   Cbuf   = (bf16*) (ws + (size_t)33554432);
    bf16*   Cv1    = (bf16*) (ws + (size_t)100663296);
    float2* munrs  = (float2*)(ws + (size_t)117440512);
    char*   wreg   = ws + (size_t)118489088;
    bf16*   Wbu_bf = (bf16*)(wreg);                  // 131072
    bf16*   Wc_bf  = (bf16*)(wreg + 131072);         // 131072
    bf16*   W1_bf  = (bf16*)(wreg + 262144);         // 131072
    bf16*   W2_bf  = (bf16*)(wreg + 393216);         // 131072
    float*  Sb     = (float*)(wreg + 524288);        // 2048
    float*  biasb  = (float*)(wreg + 526336);        // 2048
    float*  S1     = (float*)(wreg + 528384);        // 2048
    float*  bias1p = (float*)(wreg + 530432);        // 2048
    float*  gd     = (float*)(wreg + 532480);        // 1024
    float*  bd     = (float*)(wreg + 533504);        // 1024
    float4* coefs  = (float4*)(wreg + 534528);       // 4096
    bf16*   wB1    = (bf16*)(wreg + 538624);         // 163840
    bf16*   wB2    = (bf16*)(wreg + 702464);         // 163840
    float2* carry  = (float2*)(wreg + 866304);       // 2 MB

    prep_s5<<<2, 128, 0, stream>>>(Lam_re, Lam_im, B_re, B_im, C_re, C_im, log_step,
                                   ln1_g, ln1_b, D_skip,
                                   Wbu_bf, Wc_bf, Sb, biasb, gd, bd, coefs);
    prep_w1<<<2, 256, 0, stream>>>(W1, b1, ln2_g, ln2_b, W1_bf, S1, bias1p);
    prep_w2<<<2, 128, 0, stream>>>(W2, W2_bf);
    prep_wB<<<640, 256, 0, stream>>>(conv1_w, conv2_w, wB1, wB2);

    for (int i = 0; i < 2; ++i) {
        // ---- S5 sub-block: fused LN+Wbu (writes Bu + munrs), scan, Wc+resid+ud ----
        if (i == 0)
            lngemm<1, float><<<512, 1024, 0, stream>>>(
                x_in, Wbu_bf, Sb, biasb, Cbuf, munrs);
        else
            lngemm<1, bf16><<<512, 1024, 0, stream>>>(
                Xbf, Wbu_bf + 32768, Sb + 256, biasb + 256, Cbuf, munrs);
        scan_local<<<1024, 256, 0, stream>>>((unsigned int*)Cbuf, coefs + i*NST, carry);
        scan_carry<<<16, 256, 0, stream>>>(carry, coefs + i*NST);
        scan_fix<<<1024, 256, 0, stream>>>((unsigned int*)Cbuf, coefs + i*NST, carry);
        if (i == 0)
            gemm2<3, float><<<512, 1024, 0, stream>>>(
                Cbuf, Wc_bf, Xbf, nullptr, x_in, munrs, gd, bd);
        else
            gemm2<3, bf16><<<512, 1024, 0, stream>>>(
                Cbuf, Wc_bf + 32768, Xbf, nullptr, Xbf, munrs, gd + 128, bd + 128);
        // ---- MLP sub-block: fused LN+W1+gelu, W2+bias+resid ----
        lngemm<0, bf16><<<512, 1024, 0, stream>>>(
            Xbf, W1_bf + (size_t)i*32768, S1 + i*256, bias1p + i*256, Cbuf, nullptr);
        gemm2<2, bf16><<<512, 1024, 0, stream>>>(
            Cbuf, W2_bf + (size_t)i*32768, Xbf, b2 + i*HD, Xbf,
            nullptr, nullptr, nullptr);
    }

    // ---- head: conv1 (Xbf -> bf16) -> conv2+pool (-> d_out) ----
    conv1_mfma<<<512, 256, 0, stream>>>(Xbf, wB1, conv1_b, Cv1, 4096, 2048);
    conv2_pool<<<256, 256, 0, stream>>>(Cv1, wB2, conv2_b, out, 2048, 1024);
}